// Round 1
// 875.931 us; speedup vs baseline: 1.1501x; 1.1501x over previous
//
#include <hip/hip_runtime.h>
#include <stdint.h>
#include <float.h>

// B=2, L=2048, E=1024, H=16, Dk=Dv=64, top_k=32, temperature=0.7
constexpr int L = 2048;
constexpr int H = 16;
constexpr float SCALE = 0.17857142857142858f;   // 1/(sqrt(64)*0.7)
constexpr int OUT0 = 2 * 2048 * 64;             // output floats; probs follow in d_out
constexpr float QSTEP = 0.0625f;                // int8 AL quant step (scale 16/unit)

typedef float f32x4 __attribute__((ext_vector_type(4)));
typedef short s16x8 __attribute__((ext_vector_type(8)));
typedef unsigned short u16x8 __attribute__((ext_vector_type(8)));
typedef _Float16 h16x8 __attribute__((ext_vector_type(8)));

__device__ __forceinline__ float wave_fmax(float x) {
#pragma unroll
  for (int s = 32; s; s >>= 1) x = fmaxf(x, __shfl_xor(x, s));
  return x;
}
__device__ __forceinline__ float wave_fsum(float x) {
#pragma unroll
  for (int s = 32; s; s >>= 1) x += __shfl_xor(x, s);
  return x;
}
__device__ __forceinline__ int wave_isum(int x) {
#pragma unroll
  for (int s = 32; s; s >>= 1) x += __shfl_xor(x, s);
  return x;
}
__device__ __forceinline__ unsigned f2sort(float f) {
  unsigned u = __float_as_uint(f);
  return (u & 0x80000000u) ? ~u : (u | 0x80000000u);
}
__device__ __forceinline__ void lds_fence() {
  __asm__ __volatile__("s_waitcnt lgkmcnt(0)" ::: "memory");
}

// global -> LDS direct (16B per lane). Wrapper handles addrspace casts.
__device__ __forceinline__ void gload_lds16(const void* g, void* l) {
  __builtin_amdgcn_global_load_lds((const __attribute__((address_space(1))) void*)g,
                                   (__attribute__((address_space(3))) void*)l, 16, 0, 0);
}

// ---------------- fp32 -> fp16 hi/lo split (inputs pre-scaled by 256 to keep lo normal)
__global__ __launch_bounds__(256) void split_kernel(
    const float* __restrict__ q, const float* __restrict__ k,
    const float* __restrict__ wq, const float* __restrict__ wk,
    unsigned short* __restrict__ qh, unsigned short* __restrict__ ql,
    unsigned short* __restrict__ kh, unsigned short* __restrict__ kl,
    unsigned short* __restrict__ wqh, unsigned short* __restrict__ wql,
    unsigned short* __restrict__ wkh, unsigned short* __restrict__ wkl) {
  const int y = blockIdx.y;
  const float* src = (y == 0) ? q : (y == 1) ? k : (y == 2) ? wq : wk;
  unsigned short* dh = (y == 0) ? qh : (y == 1) ? kh : (y == 2) ? wqh : wkh;
  unsigned short* dl = (y == 0) ? ql : (y == 1) ? kl : (y == 2) ? wql : wkl;
  const int n = (y < 2) ? (4096 * 1024) : (1024 * 1024);
  int idx = (blockIdx.x * 256 + threadIdx.x) * 4;
  const int stride = gridDim.x * 256 * 4;
  for (; idx < n; idx += stride) {
    float4 v = *(const float4*)(src + idx);
    float xs[4] = {v.x, v.y, v.z, v.w};
    unsigned short hs[4], ls[4];
#pragma unroll
    for (int i = 0; i < 4; ++i) {
      float x = xs[i] * 256.0f;
      _Float16 hh = (_Float16)x;
      float r = x - (float)hh;
      _Float16 ll = (_Float16)r;
      hs[i] = __builtin_bit_cast(unsigned short, hh);
      ls[i] = __builtin_bit_cast(unsigned short, ll);
    }
    *(ushort4*)(dh + idx) = make_ushort4(hs[0], hs[1], hs[2], hs[3]);
    *(ushort4*)(dl + idx) = make_ushort4(ls[0], ls[1], ls[2], ls[3]);
  }
}

// ---------------- Projection GEMM via fp16 hi/lo split MFMA (fp32-grade accuracy)
// Y[m][n] = sum_e X[m][e]*W[n][e];  X,W stored as f16 hi/lo of 256*value -> acc*2^-16.
// Tile 128x128, K-chunk 64, 4 waves. LDS linear [128][64] f16 with XOR-block swizzle:
// physical 16B-block p at row r holds logical block p^(r&7) (gload_lds dest linear,
// source address pre-swizzled; frag reads apply same XOR -> 2-way banks = free).
__global__ __launch_bounds__(256) void proj_split_kernel(
    const unsigned short* __restrict__ QH, const unsigned short* __restrict__ QL,
    const unsigned short* __restrict__ KH, const unsigned short* __restrict__ KL,
    const unsigned short* __restrict__ WQH, const unsigned short* __restrict__ WQL,
    const unsigned short* __restrict__ WKH, const unsigned short* __restrict__ WKL,
    float* __restrict__ QP, float* __restrict__ KP,
    unsigned short* __restrict__ Q16, unsigned short* __restrict__ K16) {
  __shared__ unsigned short sh[4][128 * 64];   // Xh, Xl, Wh, Wl : 64 KiB
  const int t = threadIdx.x;
  const int z = blockIdx.z;
  const int m0 = blockIdx.y * 128;
  const int n0 = blockIdx.x * 128;
  const unsigned short* xh = z ? KH : QH;
  const unsigned short* xl = z ? KL : QL;
  const unsigned short* wh = z ? WKH : WQH;
  const unsigned short* wl = z ? WKL : WQL;
  float* Y = z ? KP : QP;
  unsigned short* Y16 = z ? K16 : Q16;
  const unsigned short* mats[4] = {xh + (size_t)m0 * 1024, xl + (size_t)m0 * 1024,
                                   wh + (size_t)n0 * 1024, wl + (size_t)n0 * 1024};
  const int wv = t >> 6, lane = t & 63;
  const int wm = (wv & 1) * 64, wn = (wv >> 1) * 64;
  const int fr = lane & 15, quad = lane >> 4;
  f32x4 acc[16];
#pragma unroll
  for (int i = 0; i < 16; ++i) acc[i] = (f32x4){0.f, 0.f, 0.f, 0.f};

  for (int c = 0; c < 16; ++c) {
    const int k0 = c * 64;
#pragma unroll
    for (int j = 0; j < 16; ++j) {                    // stage 64 KiB: 16 issues/thread
      const int mat = j >> 2;
      const int idx = (j & 3) * 256 + t;              // 1024 16B-blocks per matrix
      const int r = idx >> 3, p = idx & 7;
      const int sb = p ^ (r & 7);                     // inverse swizzle on source
      gload_lds16(mats[mat] + (size_t)r * 1024 + k0 + sb * 8, &sh[mat][idx * 8]);
    }
    __syncthreads();                                  // drains vmcnt before barrier
#pragma unroll
    for (int kh2 = 0; kh2 < 2; ++kh2) {
      h16x8 ah[4], alv[4], bh[4], blv[4];
#pragma unroll
      for (int mi = 0; mi < 4; ++mi) {
        int row = wm + mi * 16 + fr;
        int pp = (kh2 * 4 + quad) ^ (row & 7);
        ah[mi]  = *(const h16x8*)&sh[0][row * 64 + pp * 8];
        alv[mi] = *(const h16x8*)&sh[1][row * 64 + pp * 8];
      }
#pragma unroll
      for (int ni = 0; ni < 4; ++ni) {
        int row = wn + ni * 16 + fr;
        int pp = (kh2 * 4 + quad) ^ (row & 7);
        bh[ni]  = *(const h16x8*)&sh[2][row * 64 + pp * 8];
        blv[ni] = *(const h16x8*)&sh[3][row * 64 + pp * 8];
      }
#pragma unroll
      for (int mi = 0; mi < 4; ++mi)
#pragma unroll
        for (int ni = 0; ni < 4; ++ni) {
          acc[mi * 4 + ni] = __builtin_amdgcn_mfma_f32_16x16x32_f16(ah[mi], bh[ni], acc[mi * 4 + ni], 0, 0, 0);
          acc[mi * 4 + ni] = __builtin_amdgcn_mfma_f32_16x16x32_f16(ah[mi], blv[ni], acc[mi * 4 + ni], 0, 0, 0);
          acc[mi * 4 + ni] = __builtin_amdgcn_mfma_f32_16x16x32_f16(alv[mi], bh[ni], acc[mi * 4 + ni], 0, 0, 0);
        }
    }
    __syncthreads();                                  // frag reads done before restage
  }
  // epilogue: C layout col=lane&15, row=quad*4+reg; emit fp32 + fp16 copy (unscaled)
#pragma unroll
  for (int mi = 0; mi < 4; ++mi)
#pragma unroll
    for (int ni = 0; ni < 4; ++ni) {
      int col = n0 + wn + ni * 16 + fr;
      int h = col >> 6, d = col & 63;
#pragma unroll
      for (int r = 0; r < 4; ++r) {
        int m = m0 + wm + mi * 16 + quad * 4 + r;
        int b = m >> 11, l = m & 2047;
        size_t off = (((size_t)b * H + h) * L + l) * 64 + d;
        float val = acc[mi * 4 + ni][r] * (1.0f / 65536.0f);
        Y[off] = val;
        _Float16 hf = (_Float16)val;
        Y16[off] = __builtin_bit_cast(unsigned short, hf);
      }
    }
}

// ---------------- Projection GEMM (fp32 scalar path — kept for V, K=64 only)
template <int K, bool EMIT>
__global__ __launch_bounds__(256) void proj_kernel(const float* __restrict__ X,
                                                   const float* __restrict__ W,
                                                   float* __restrict__ Y,
                                                   unsigned short* __restrict__ Yb,
                                                   float bscale) {
  __shared__ float As[16][128];
  __shared__ float Bs[16][64];
  const int t = threadIdx.x;
  const int tx = t & 15;
  const int ty = t >> 4;
  const int m0 = blockIdx.y * 128;
  const int n0 = blockIdx.x * 64;
  const int ar = t >> 1, ac = (t & 1) * 8;
  const int br = t >> 2, bc = (t & 3) * 4;
  const float* xg = X + (size_t)(m0 + ar) * K + ac;
  const float* wg = W + (size_t)(n0 + br) * K + bc;
  float acc[8][4] = {};
  for (int k0 = 0; k0 < K; k0 += 16) {
    float4 a0 = *(const float4*)(xg + k0);
    float4 a1 = *(const float4*)(xg + k0 + 4);
    float4 b0 = *(const float4*)(wg + k0);
    __syncthreads();
    As[ac + 0][ar] = a0.x; As[ac + 1][ar] = a0.y; As[ac + 2][ar] = a0.z; As[ac + 3][ar] = a0.w;
    As[ac + 4][ar] = a1.x; As[ac + 5][ar] = a1.y; As[ac + 6][ar] = a1.z; As[ac + 7][ar] = a1.w;
    Bs[bc + 0][br] = b0.x; Bs[bc + 1][br] = b0.y; Bs[bc + 2][br] = b0.z; Bs[bc + 3][br] = b0.w;
    __syncthreads();
#pragma unroll
    for (int kk = 0; kk < 16; ++kk) {
      float4 av0 = *(const float4*)&As[kk][ty * 8];
      float4 av1 = *(const float4*)&As[kk][ty * 8 + 4];
      float4 bv = *(const float4*)&Bs[kk][tx * 4];
      float ar8[8] = {av0.x, av0.y, av0.z, av0.w, av1.x, av1.y, av1.z, av1.w};
      float br4[4] = {bv.x, bv.y, bv.z, bv.w};
#pragma unroll
      for (int i = 0; i < 8; ++i)
#pragma unroll
        for (int j = 0; j < 4; ++j) acc[i][j] = fmaf(ar8[i], br4[j], acc[i][j]);
    }
  }
  const int n = n0 + tx * 4;
  const int h = n >> 6, d = n & 63;
#pragma unroll
  for (int i = 0; i < 8; ++i) {
    int mm = m0 + ty * 8 + i;
    int b = mm >> 11, l = mm & 2047;
    size_t off = (((size_t)b * H + h) * L + l) * 64 + d;
    *(float4*)&Y[off] = make_float4(acc[i][0], acc[i][1], acc[i][2], acc[i][3]);
  }
}

// ---------------- Approx logits, f16 MFMA -> int8 AL (quant = logit*16, clamp +-127)
constexpr int ALD = 72;    // padded LDS stride (f16 units) for frag reads
constexpr int CTB = 136;   // int8 CT stride in bytes (8-aligned, non-pow2)

__global__ __launch_bounds__(256) void alogits_kernel(const unsigned short* __restrict__ Qb,
                                                      const unsigned short* __restrict__ Kb,
                                                      char* __restrict__ AL) {
  __shared__ union {
    unsigned short qk[2][128 * ALD];   // 36864 B
    char ct[128 * CTB];                // 17408 B
  } sh;
  const int t = threadIdx.x;
  const int bh = blockIdx.z;
  const int m0 = blockIdx.y * 128, n0 = blockIdx.x * 128;
  const unsigned short* Qg = Qb + (size_t)bh * L * 64 + (size_t)m0 * 64;
  const unsigned short* Kg = Kb + (size_t)bh * L * 64 + (size_t)n0 * 64;
#pragma unroll
  for (int i = 0; i < 4; ++i) {
    int blk = t * 4 + i;               // 0..1023 : 128 rows x 8 blocks(16B)
    int r = blk >> 3, lb = blk & 7;
    *(u16x8*)&sh.qk[0][r * ALD + lb * 8] = *(const u16x8*)&Qg[r * 64 + lb * 8];
    *(u16x8*)&sh.qk[1][r * ALD + lb * 8] = *(const u16x8*)&Kg[r * 64 + lb * 8];
  }
  __syncthreads();
  const int wv = t >> 6, lane = t & 63;
  const int wm = (wv & 1) * 64, wn = (wv >> 1) * 64;
  const int fr = lane & 15, quad = lane >> 4;
  f32x4 acc[16];
#pragma unroll
  for (int i = 0; i < 16; ++i) acc[i] = (f32x4){0.f, 0.f, 0.f, 0.f};
#pragma unroll
  for (int kh = 0; kh < 2; ++kh) {
    h16x8 a[4], b[4];
#pragma unroll
    for (int mi = 0; mi < 4; ++mi)
      a[mi] = *(const h16x8*)&sh.qk[0][(wm + mi * 16 + fr) * ALD + kh * 32 + quad * 8];
#pragma unroll
    for (int ni = 0; ni < 4; ++ni)
      b[ni] = *(const h16x8*)&sh.qk[1][(wn + ni * 16 + fr) * ALD + kh * 32 + quad * 8];
#pragma unroll
    for (int mi = 0; mi < 4; ++mi)
#pragma unroll
      for (int ni = 0; ni < 4; ++ni)
        acc[mi * 4 + ni] = __builtin_amdgcn_mfma_f32_16x16x32_f16(
            a[mi], b[ni], acc[mi * 4 + ni], 0, 0, 0);
  }
  __syncthreads();                                           // reuse LDS as CT
#pragma unroll
  for (int mi = 0; mi < 4; ++mi)
#pragma unroll
    for (int ni = 0; ni < 4; ++ni) {
      int col = wn + ni * 16 + fr;
#pragma unroll
      for (int r = 0; r < 4; ++r) {
        int rowl = wm + mi * 16 + quad * 4 + r;
        float sc = acc[mi * 4 + ni][r] * 2.8571428571428572f;  // SCALE*16 (inputs unscaled f16)
        sc = fminf(fmaxf(sc, -127.0f), 127.0f);
        sh.ct[rowl * CTB + col] = (char)__float2int_rn(sc);
      }
    }
  __syncthreads();
  // Coalesced NT store: 16-lane quarter writes one contiguous 128 B row (2 full lines)
  char* Abase = AL + (size_t)bh * L * L;
  const int rq = lane >> 4;            // 0..3
  const int cq = (lane & 15) * 8;      // 0..120, 8 B per lane
#pragma unroll
  for (int it = 0; it < 8; ++it) {
    int row = wv * 32 + it * 4 + rq;
    uint2 v8 = *(const uint2*)&sh.ct[row * CTB + cq];
    __builtin_nontemporal_store(v8.x, (unsigned*)&Abase[(size_t)(m0 + row) * L + n0 + cq]);
    __builtin_nontemporal_store(v8.y, (unsigned*)&Abase[(size_t)(m0 + row) * L + n0 + cq + 4]);
  }
}

// ---------------- Select: int8 approx filter -> exact fp32 recompute -> softmax -> probs + PV
// One wave per row; lane owns keys (u2*64+lane)*4 + b  (u2=0..7, b=0..3).
__global__ __launch_bounds__(256) void select_kernel(const char* __restrict__ AL,
                                                     const float* __restrict__ Qp,
                                                     const float* __restrict__ Kp,
                                                     const float* __restrict__ Vp,
                                                     float* __restrict__ Probs,
                                                     float* __restrict__ Mixed) {
  __shared__ float prow[4][2048];
  __shared__ float qbuf[4][64];
  __shared__ float cbuf[4][64];
  __shared__ int ibufc[4][64];
  __shared__ float pbuf[4][32];
  __shared__ int ibuf[4][32];
  const int lane = threadIdx.x & 63;
  const int w = threadIdx.x >> 6;
  const int row = blockIdx.x * 4 + w;
  const int bh = row >> 11;
  const int q = row & 2047;
  const unsigned long long below = (lane == 63) ? 0x7fffffffffffffffull
                                                : ((1ull << lane) - 1ull);
  const unsigned* Arow = (const unsigned*)(AL + (size_t)row * 2048);

  float lg[32];
#pragma unroll
  for (int u2 = 0; u2 < 8; ++u2) {
    unsigned dw = __builtin_nontemporal_load(Arow + u2 * 64 + lane);
#pragma unroll
    for (int b = 0; b < 4; ++b)
      lg[u2 * 4 + b] = (float)((char)(dw >> (8 * b))) * QSTEP;
  }
  // zero prow early (wave-local)
#pragma unroll
  for (int u = 0; u < 32; ++u) prow[w][u * 64 + lane] = 0.f;
  // stage fp32 Q row (unscaled)
  if (lane < 16)
    *(float4*)&qbuf[w][lane * 4] = *(const float4*)&Qp[((size_t)bh * L + q) * 64 + lane * 4];

  float m = lg[0];
#pragma unroll
  for (int u = 1; u < 32; ++u) m = fmaxf(m, lg[u]);
  m = wave_fmax(m);

  // ---- T32a = 32nd-largest approx value (bit-exact on approx grid)
  float T = 0.f;
  bool found = false;
  float cut = m - 2.2f;
  float lo = 0.f, hi = m;
  bool has_lo = false;
  for (int attempt = 0; attempt < 8 && !found; ++attempt) {
    int c = 0;
#pragma unroll
    for (int u = 0; u < 32; ++u) c += (lg[u] > cut) ? 1 : 0;
    c = wave_isum(c);
    if (c < 32) {
      hi = cut;
      cut = has_lo ? 0.5f * (lo + cut) : (cut - 0.45f);
    } else if (c > 64) {
      lo = cut; has_lo = true;
      cut = 0.5f * (cut + hi);
    } else {
      int base = 0;                    // slot order arbitrary (set semantics)
#pragma unroll
      for (int u = 0; u < 32; ++u) {
        bool cd = lg[u] > cut;
        unsigned long long mk = __ballot(cd);
        if (cd) cbuf[w][base + __popcll(mk & below)] = lg[u];
        base += __popcll(mk);
      }
      lds_fence();
      float v2 = (lane < c) ? cbuf[w][lane] : -FLT_MAX;
#pragma unroll
      for (int size = 2; size <= 64; size <<= 1)
#pragma unroll
        for (int stride = size >> 1; stride; stride >>= 1) {
          float pv = __shfl_xor(v2, stride);
          bool lower = (lane & stride) == 0;
          bool asc = (lane & size) == 0;
          v2 = (lower == asc) ? fminf(v2, pv) : fmaxf(v2, pv);
        }
      T = __shfl(v2, 32);
      found = true;
    }
  }
  if (!found) {   // exact radix bisect on approx bits
    unsigned tb = 0;
    for (int bit = 31; bit >= 0; --bit) {
      unsigned cand = tb | (1u << bit);
      int c = 0;
#pragma unroll
      for (int u = 0; u < 32; ++u) c += (f2sort(lg[u]) >= cand) ? 1 : 0;
      c = wave_isum(c);
      if (c >= 32) tb = cand;
    }
    T = (tb & 0x80000000u) ? __uint_as_float(tb & 0x7fffffffu) : __uint_as_float(~tb);
  }

  // ---- candidate set: largest margin whose count fits the 64 recompute slots
  float theta = T;
  int c2 = 0;
  const float margs[5] = {0.40f, 0.25f, 0.15f, 0.08f, 0.0f};
#pragma unroll
  for (int a = 0; a < 5; ++a) {
    float th = T - margs[a];
    int c = 0;
#pragma unroll
    for (int u = 0; u < 32; ++u) c += (lg[u] >= th) ? 1 : 0;
    c = wave_isum(c);
    theta = th; c2 = c;
    if (c <= 64) break;
  }
  if (c2 > 64) c2 = 64;   // astronomically unlikely tie flood

  // rank-scatter candidate flat indices (slot order arbitrary)
  {
    int base = 0;
#pragma unroll
    for (int u = 0; u < 32; ++u) {
      bool cd = lg[u] >= theta;
      unsigned long long mk = __ballot(cd);
      if (cd) {
        int s = base + __popcll(mk & below);
        if (s < 64) ibufc[w][s] = ((u >> 2) * 64 + lane) * 4 + (u & 3);
      }
      base += __popcll(mk);
    }
  }
  lds_fence();

  // ---- exact fp32 recompute for candidates (one per lane)
  int myi = (lane < c2) ? ibufc[w][lane] : 0x7fffffff;
  float vex = -FLT_MAX;
  if (lane < c2) {
    const float4* K4 = (const float4*)(Kp + ((size_t)bh * L + myi) * 64);
    const float4* Q4 = (const float4*)&qbuf[w][0];
    float acc = 0.f;
#pragma unroll
    for (int dq = 0; dq < 16; ++dq) {
      float4 kv = K4[dq];
      float4 qv = Q4[dq];
      acc = fmaf(qv.x, kv.x, acc);
      acc = fmaf(qv.y, kv.y, acc);
      acc = fmaf(qv.z, kv.z, acc);
      acc = fmaf(qv.w, kv.w, acc);
    }
    vex = (acc * 0.125f) / 0.7f;   // matches ref: (q/8)@k then /0.7
  }

  // ---- sort 64 lanes by (value desc, index asc): key ascending
  unsigned long long key = ((unsigned long long)(~f2sort(vex)) << 32) | (unsigned)myi;
#pragma unroll
  for (int size = 2; size <= 64; size <<= 1)
#pragma unroll
    for (int stride = size >> 1; stride; stride >>= 1) {
      unsigned long long pk = __shfl_xor(key, stride);
      unsigned long long mn = key < pk ? key : pk;
      unsigned long long mx = key < pk ? pk : key;
      bool keepmin = ((lane & stride) == 0) == ((lane & size) == 0);
      key = keepmin ? mn : mx;
    }
  unsigned uv = ~(unsigned)(key >> 32);
  float vs = __uint_as_float((uv & 0x80000000u) ? (uv & 0x7fffffffu) : ~uv);
  int sidx = (int)(unsigned)(key & 0xffffffffull);

  // ---- softmax over kept 32 (lanes 0..31 sorted best-first)
  float vmax = __shfl(vs, 0);
  float e = (lane < 32) ? __expf(vs - vmax) : 0.f;
  float S = wave_fsum(e);
  float p = e / S;
  if (lane < 32) {
    pbuf[w][lane] = p;
    ibuf[w][lane] = sidx;
    prow[w][sidx] = p;
  }
  lds_fence();

  // ---- dense probs row write (zeros + 32 kept)
  float* Prow = Probs + (size_t)row * 2048;
#pragma unroll
  for (int u = 0; u < 32; ++u)
    __builtin_nontemporal_store(prow[w][u * 64 + lane], Prow + u * 64 + lane);

  // ---- sparse PV
  const float* Vb = Vp + (size_t)bh * L * 64;
  float accv = 0.f;
#pragma unroll
  for (int i = 0; i < 32; ++i)
    accv = fmaf(pbuf[w][i], Vb[(size_t)ibuf[w][i] * 64 + lane], accv);
  const int bb = bh >> 4, hh = bh & 15;
  Mixed[((size_t)(bb * 2048 + q)) * 1024 + hh * 64 + lane] = accv;
}

// ---------------- Output FC: Out[m][n] = sum_k Mixed[m][k] * Wfc[n][k]  (M=4096,N=64,K=1024)
__global__ __launch_bounds__(256) void fc_kernel(const float* __restrict__ Mx,
                                                 const float* __restrict__ Wfc,
                                                 float* __restrict__ Out) {
  __shared__ float As[32][64];
  __shared__ float Ws[64][64];
  const int t = threadIdx.x;
  const int tx = t & 15;
  const int ty = t >> 4;
  const int m0 = blockIdx.x * 32;
  float acc[2][4] = {};
  for (int k0 = 0; k0 < 1024; k0 += 64) {
    __syncthreads();
    {
      int lin = t * 8;
      int rr = lin >> 6, kk = lin & 63;
      *(float4*)&As[rr][kk] = *(const float4*)&Mx[(size_t)(m0 + rr) * 1024 + k0 + kk];
      *(float4*)&As[rr][kk + 4] = *(const float4*)&Mx[(size_t)(m0 + rr) * 1024 + k0 + kk + 4];
    }
    {
      int n = t >> 2;
      int kq = (t & 3) * 16;
#pragma unroll
      for (int u = 0; u < 4; ++u) {
        float4 wv = *(const float4*)&Wfc[(size_t)n * 1024 + k0 + kq + u * 4];
        Ws[kq + u * 4 + 0][n] = wv.x;
        Ws[kq + u * 4 + 1][n] = wv.y;
        Ws[kq + u * 4 + 2][n] = wv.z;
        Ws[kq + u * 4 + 3][n] = wv.w;
      }
    }
    __syncthreads();
#pragma unroll
    for (int kk = 0; kk < 64; ++kk) {
      float a0 = As[ty][kk], a1 = As[ty + 16][kk];
      float4 wv = *(const float4*)&Ws[kk][tx * 4];
      float wr[4] = {wv.x, wv.y, wv.z, wv.w};
#pragma unroll
      for (int j = 0; j < 4; ++j) {
        acc[0][j] = fmaf(a0, wr[j], acc[0][j]);
        acc[1][j] = fmaf(a1, wr[j], acc[1][j]);
      }
    }
  }
#pragma unroll
  for (int i = 0; i < 2; ++i) {
    int mm = m0 + ty + i * 16;
    *(float4*)&Out[(size_t)mm * 64 + tx * 4] =
        make_float4(acc[i][0], acc[i][1], acc[i][2], acc[i][3]);
  }
}

extern "C" void kernel_launch(void* const* d_in, const int* in_sizes, int n_in,
                              void* d_out, int out_size, void* d_ws, size_t ws_size,
                              hipStream_t stream) {
  const float* q    = (const float*)d_in[0];
  const float* k    = (const float*)d_in[1];
  const float* v    = (const float*)d_in[2];
  const float* w_q  = (const float*)d_in[3];
  const float* w_k  = (const float*)d_in[4];
  const float* w_v  = (const float*)d_in[5];
  const float* w_fc = (const float*)d_in[6];

  float* out = (float*)d_out;
  float* probs = out + OUT0;

  float* ws = (float*)d_ws;
  float* q_proj = ws;                          // [B][H][L][64] fp32 (UNSCALED)
  float* k_proj = ws + 4194304;
  float* v_proj = ws + 8388608;
  float* mixed  = ws + 12582912;               // [B*L][1024]
  unsigned short* qb = (unsigned short*)(ws + 16777216);   // f16(q_proj) for alogits
  unsigned short* kb = (unsigned short*)(ws + 18874368);   // f16(k_proj)
  char* al = (char*)(ws + 20971520);           // approx logits int8 [bh][i][j], 128 MB

  // fp16 hi/lo split arrays (inputs * 256), placed after AL (ws fill shows ~2.1 GB)
  unsigned short* qh  = (unsigned short*)((char*)d_ws + 234881024);  // 224 MiB
  unsigned short* ql  = qh + 4194304;
  unsigned short* kh  = ql + 4194304;
  unsigned short* kl  = kh + 4194304;
  unsigned short* wqh = kl + 4194304;
  unsigned short* wql = wqh + 1048576;
  unsigned short* wkh = wql + 1048576;
  unsigned short* wkl = wkh + 1048576;

  dim3 blk(256);
  split_kernel<<<dim3(1024, 4), blk, 0, stream>>>(q, k, w_q, w_k,
                                                  qh, ql, kh, kl, wqh, wql, wkh, wkl);
  proj_split_kernel<<<dim3(8, 32, 2), blk, 0, stream>>>(qh, ql, kh, kl,
                                                        wqh, wql, wkh, wkl,
                                                        q_proj, k_proj, qb, kb);
  proj_kernel<64, false><<<dim3(16, 32), blk, 0, stream>>>(v, w_v, v_proj, nullptr, 1.0f);
  alogits_kernel<<<dim3(16, 16, 32), blk, 0, stream>>>(qb, kb, al);
  select_kernel<<<dim3(16384), blk, 0, stream>>>(al, q_proj, k_proj, v_proj, probs, mixed);
  fc_kernel<<<dim3(128), blk, 0, stream>>>(mixed, w_fc, out);
}

// Round 2
// 862.661 us; speedup vs baseline: 1.1678x; 1.0154x over previous
//
#include <hip/hip_runtime.h>
#include <stdint.h>
#include <float.h>

// B=2, L=2048, E=1024, H=16, Dk=Dv=64, top_k=32, temperature=0.7
constexpr int L = 2048;
constexpr int H = 16;
constexpr float SCALE = 0.17857142857142858f;   // 1/(sqrt(64)*0.7)
constexpr int OUT0 = 2 * 2048 * 64;             // output floats; probs follow in d_out
constexpr float QSTEP = 0.0625f;                // int8 AL quant step (scale 16/unit)

typedef float f32x4 __attribute__((ext_vector_type(4)));
typedef short s16x8 __attribute__((ext_vector_type(8)));
typedef unsigned short u16x8 __attribute__((ext_vector_type(8)));
typedef _Float16 h16x8 __attribute__((ext_vector_type(8)));

__device__ __forceinline__ float wave_fmax(float x) {
#pragma unroll
  for (int s = 32; s; s >>= 1) x = fmaxf(x, __shfl_xor(x, s));
  return x;
}
__device__ __forceinline__ float wave_fsum(float x) {
#pragma unroll
  for (int s = 32; s; s >>= 1) x += __shfl_xor(x, s);
  return x;
}
__device__ __forceinline__ int wave_isum(int x) {
#pragma unroll
  for (int s = 32; s; s >>= 1) x += __shfl_xor(x, s);
  return x;
}
__device__ __forceinline__ unsigned f2sort(float f) {
  unsigned u = __float_as_uint(f);
  return (u & 0x80000000u) ? ~u : (u | 0x80000000u);
}
__device__ __forceinline__ void lds_fence() {
  __asm__ __volatile__("s_waitcnt lgkmcnt(0)" ::: "memory");
}

// global -> LDS direct (16B per lane). Wrapper handles addrspace casts.
__device__ __forceinline__ void gload_lds16(const void* g, void* l) {
  __builtin_amdgcn_global_load_lds((const __attribute__((address_space(1))) void*)g,
                                   (__attribute__((address_space(3))) void*)l, 16, 0, 0);
}

// ---------------- fp32 -> fp16 hi/lo split (inputs pre-scaled by 256 to keep lo normal)
__global__ __launch_bounds__(256) void split_kernel(
    const float* __restrict__ q, const float* __restrict__ k,
    const float* __restrict__ wq, const float* __restrict__ wk,
    unsigned short* __restrict__ qh, unsigned short* __restrict__ ql,
    unsigned short* __restrict__ kh, unsigned short* __restrict__ kl,
    unsigned short* __restrict__ wqh, unsigned short* __restrict__ wql,
    unsigned short* __restrict__ wkh, unsigned short* __restrict__ wkl) {
  const int y = blockIdx.y;
  const float* src = (y == 0) ? q : (y == 1) ? k : (y == 2) ? wq : wk;
  unsigned short* dh = (y == 0) ? qh : (y == 1) ? kh : (y == 2) ? wqh : wkh;
  unsigned short* dl = (y == 0) ? ql : (y == 1) ? kl : (y == 2) ? wql : wkl;
  const int n = (y < 2) ? (4096 * 1024) : (1024 * 1024);
  int idx = (blockIdx.x * 256 + threadIdx.x) * 4;
  const int stride = gridDim.x * 256 * 4;
  for (; idx < n; idx += stride) {
    float4 v = *(const float4*)(src + idx);
    float xs[4] = {v.x, v.y, v.z, v.w};
    unsigned short hs[4], ls[4];
#pragma unroll
    for (int i = 0; i < 4; ++i) {
      float x = xs[i] * 256.0f;
      _Float16 hh = (_Float16)x;
      float r = x - (float)hh;
      _Float16 ll = (_Float16)r;
      hs[i] = __builtin_bit_cast(unsigned short, hh);
      ls[i] = __builtin_bit_cast(unsigned short, ll);
    }
    *(ushort4*)(dh + idx) = make_ushort4(hs[0], hs[1], hs[2], hs[3]);
    *(ushort4*)(dl + idx) = make_ushort4(ls[0], ls[1], ls[2], ls[3]);
  }
}

// ---------------- Projection GEMM via fp16 hi/lo split MFMA (fp32-grade accuracy)
// Y[m][n] = sum_e X[m][e]*W[n][e];  X,W stored as f16 hi/lo of 256*value -> acc*2^-16.
// Tile 128x128, K-chunk 64, 4 waves. LDS linear [128][64] f16 with XOR-block swizzle.
// Schedule: per chunk, ds_read ALL frags -> regs, barrier, issue NEXT chunk's
// global_load_lds into the same buffer, then MFMA (load latency hides under MFMA).
__global__ __launch_bounds__(256, 2) void proj_split_kernel(
    const unsigned short* __restrict__ QH, const unsigned short* __restrict__ QL,
    const unsigned short* __restrict__ KH, const unsigned short* __restrict__ KL,
    const unsigned short* __restrict__ WQH, const unsigned short* __restrict__ WQL,
    const unsigned short* __restrict__ WKH, const unsigned short* __restrict__ WKL,
    float* __restrict__ QP, float* __restrict__ KP,
    unsigned short* __restrict__ Q16, unsigned short* __restrict__ K16) {
  __shared__ unsigned short sh[4][128 * 64];   // Xh, Xl, Wh, Wl : 64 KiB
  const int t = threadIdx.x;
  const int z = blockIdx.z;
  const int m0 = blockIdx.y * 128;
  const int n0 = blockIdx.x * 128;
  const unsigned short* xh = z ? KH : QH;
  const unsigned short* xl = z ? KL : QL;
  const unsigned short* wh = z ? WKH : WQH;
  const unsigned short* wl = z ? WKL : WQL;
  float* Y = z ? KP : QP;
  unsigned short* Y16 = z ? K16 : Q16;
  const unsigned short* mats[4] = {xh + (size_t)m0 * 1024, xl + (size_t)m0 * 1024,
                                   wh + (size_t)n0 * 1024, wl + (size_t)n0 * 1024};
  const int wv = t >> 6, lane = t & 63;
  const int wm = (wv & 1) * 64, wn = (wv >> 1) * 64;
  const int fr = lane & 15, quad = lane >> 4;
  f32x4 acc[16];
#pragma unroll
  for (int i = 0; i < 16; ++i) acc[i] = (f32x4){0.f, 0.f, 0.f, 0.f};

  // stage one K-chunk (64 KiB): 16 gload_lds issues/thread, source pre-inverse-swizzled
#define STAGE(cc)                                                              \
  {                                                                            \
    const int k0s = (cc) * 64;                                                 \
    _Pragma("unroll") for (int j = 0; j < 16; ++j) {                           \
      const int mat = j >> 2;                                                  \
      const int idx = (j & 3) * 256 + t;                                       \
      const int r = idx >> 3, p = idx & 7;                                     \
      const int sb = p ^ (r & 7);                                              \
      gload_lds16(mats[mat] + (size_t)r * 1024 + k0s + sb * 8, &sh[mat][idx * 8]); \
    }                                                                          \
  }

  STAGE(0);
  for (int c = 0; c < 16; ++c) {
    __syncthreads();                   // vmcnt(0): stage(c) landed in LDS
    h16x8 ah[2][4], alv[2][4], bh[2][4], blv[2][4];
#pragma unroll
    for (int kh2 = 0; kh2 < 2; ++kh2) {
#pragma unroll
      for (int mi = 0; mi < 4; ++mi) {
        int row = wm + mi * 16 + fr;
        int pp = (kh2 * 4 + quad) ^ (row & 7);
        ah[kh2][mi]  = *(const h16x8*)&sh[0][row * 64 + pp * 8];
        alv[kh2][mi] = *(const h16x8*)&sh[1][row * 64 + pp * 8];
      }
#pragma unroll
      for (int ni = 0; ni < 4; ++ni) {
        int row = wn + ni * 16 + fr;
        int pp = (kh2 * 4 + quad) ^ (row & 7);
        bh[kh2][ni]  = *(const h16x8*)&sh[2][row * 64 + pp * 8];
        blv[kh2][ni] = *(const h16x8*)&sh[3][row * 64 + pp * 8];
      }
    }
    __syncthreads();                   // all waves' ds_reads done -> LDS reusable
    if (c < 15) STAGE(c + 1);          // prefetch next chunk under the MFMAs
#pragma unroll
    for (int kh2 = 0; kh2 < 2; ++kh2)
#pragma unroll
      for (int mi = 0; mi < 4; ++mi)
#pragma unroll
        for (int ni = 0; ni < 4; ++ni) {
          acc[mi * 4 + ni] = __builtin_amdgcn_mfma_f32_16x16x32_f16(ah[kh2][mi], bh[kh2][ni], acc[mi * 4 + ni], 0, 0, 0);
          acc[mi * 4 + ni] = __builtin_amdgcn_mfma_f32_16x16x32_f16(ah[kh2][mi], blv[kh2][ni], acc[mi * 4 + ni], 0, 0, 0);
          acc[mi * 4 + ni] = __builtin_amdgcn_mfma_f32_16x16x32_f16(alv[kh2][mi], bh[kh2][ni], acc[mi * 4 + ni], 0, 0, 0);
        }
  }
#undef STAGE
  // epilogue: C layout col=lane&15, row=quad*4+reg; emit fp32 + fp16 copy (unscaled)
#pragma unroll
  for (int mi = 0; mi < 4; ++mi)
#pragma unroll
    for (int ni = 0; ni < 4; ++ni) {
      int col = n0 + wn + ni * 16 + fr;
      int h = col >> 6, d = col & 63;
#pragma unroll
      for (int r = 0; r < 4; ++r) {
        int m = m0 + wm + mi * 16 + quad * 4 + r;
        int b = m >> 11, l = m & 2047;
        size_t off = (((size_t)b * H + h) * L + l) * 64 + d;
        float val = acc[mi * 4 + ni][r] * (1.0f / 65536.0f);
        Y[off] = val;
        _Float16 hf = (_Float16)val;
        Y16[off] = __builtin_bit_cast(unsigned short, hf);
      }
    }
}

// ---------------- Projection GEMM (fp32 scalar path — kept for V, K=64 only)
template <int K, bool EMIT>
__global__ __launch_bounds__(256) void proj_kernel(const float* __restrict__ X,
                                                   const float* __restrict__ W,
                                                   float* __restrict__ Y,
                                                   unsigned short* __restrict__ Yb,
                                                   float bscale) {
  __shared__ float As[16][128];
  __shared__ float Bs[16][64];
  const int t = threadIdx.x;
  const int tx = t & 15;
  const int ty = t >> 4;
  const int m0 = blockIdx.y * 128;
  const int n0 = blockIdx.x * 64;
  const int ar = t >> 1, ac = (t & 1) * 8;
  const int br = t >> 2, bc = (t & 3) * 4;
  const float* xg = X + (size_t)(m0 + ar) * K + ac;
  const float* wg = W + (size_t)(n0 + br) * K + bc;
  float acc[8][4] = {};
  for (int k0 = 0; k0 < K; k0 += 16) {
    float4 a0 = *(const float4*)(xg + k0);
    float4 a1 = *(const float4*)(xg + k0 + 4);
    float4 b0 = *(const float4*)(wg + k0);
    __syncthreads();
    As[ac + 0][ar] = a0.x; As[ac + 1][ar] = a0.y; As[ac + 2][ar] = a0.z; As[ac + 3][ar] = a0.w;
    As[ac + 4][ar] = a1.x; As[ac + 5][ar] = a1.y; As[ac + 6][ar] = a1.z; As[ac + 7][ar] = a1.w;
    Bs[bc + 0][br] = b0.x; Bs[bc + 1][br] = b0.y; Bs[bc + 2][br] = b0.z; Bs[bc + 3][br] = b0.w;
    __syncthreads();
#pragma unroll
    for (int kk = 0; kk < 16; ++kk) {
      float4 av0 = *(const float4*)&As[kk][ty * 8];
      float4 av1 = *(const float4*)&As[kk][ty * 8 + 4];
      float4 bv = *(const float4*)&Bs[kk][tx * 4];
      float ar8[8] = {av0.x, av0.y, av0.z, av0.w, av1.x, av1.y, av1.z, av1.w};
      float br4[4] = {bv.x, bv.y, bv.z, bv.w};
#pragma unroll
      for (int i = 0; i < 8; ++i)
#pragma unroll
        for (int j = 0; j < 4; ++j) acc[i][j] = fmaf(ar8[i], br4[j], acc[i][j]);
    }
  }
  const int n = n0 + tx * 4;
  const int h = n >> 6, d = n & 63;
#pragma unroll
  for (int i = 0; i < 8; ++i) {
    int mm = m0 + ty * 8 + i;
    int b = mm >> 11, l = mm & 2047;
    size_t off = (((size_t)b * H + h) * L + l) * 64 + d;
    *(float4*)&Y[off] = make_float4(acc[i][0], acc[i][1], acc[i][2], acc[i][3]);
  }
}

// ---------------- Approx logits, f16 MFMA -> int8 AL (quant = logit*16, clamp +-127)
constexpr int ALD = 72;    // padded LDS stride (f16 units) for frag reads
constexpr int CTB = 136;   // int8 CT stride in bytes (8-aligned, non-pow2)

__global__ __launch_bounds__(256) void alogits_kernel(const unsigned short* __restrict__ Qb,
                                                      const unsigned short* __restrict__ Kb,
                                                      char* __restrict__ AL) {
  __shared__ union {
    unsigned short qk[2][128 * ALD];   // 36864 B
    char ct[128 * CTB];                // 17408 B
  } sh;
  const int t = threadIdx.x;
  const int bh = blockIdx.z;
  const int m0 = blockIdx.y * 128, n0 = blockIdx.x * 128;
  const unsigned short* Qg = Qb + (size_t)bh * L * 64 + (size_t)m0 * 64;
  const unsigned short* Kg = Kb + (size_t)bh * L * 64 + (size_t)n0 * 64;
#pragma unroll
  for (int i = 0; i < 4; ++i) {
    int blk = t * 4 + i;               // 0..1023 : 128 rows x 8 blocks(16B)
    int r = blk >> 3, lb = blk & 7;
    *(u16x8*)&sh.qk[0][r * ALD + lb * 8] = *(const u16x8*)&Qg[r * 64 + lb * 8];
    *(u16x8*)&sh.qk[1][r * ALD + lb * 8] = *(const u16x8*)&Kg[r * 64 + lb * 8];
  }
  __syncthreads();
  const int wv = t >> 6, lane = t & 63;
  const int wm = (wv & 1) * 64, wn = (wv >> 1) * 64;
  const int fr = lane & 15, quad = lane >> 4;
  f32x4 acc[16];
#pragma unroll
  for (int i = 0; i < 16; ++i) acc[i] = (f32x4){0.f, 0.f, 0.f, 0.f};
#pragma unroll
  for (int kh = 0; kh < 2; ++kh) {
    h16x8 a[4], b[4];
#pragma unroll
    for (int mi = 0; mi < 4; ++mi)
      a[mi] = *(const h16x8*)&sh.qk[0][(wm + mi * 16 + fr) * ALD + kh * 32 + quad * 8];
#pragma unroll
    for (int ni = 0; ni < 4; ++ni)
      b[ni] = *(const h16x8*)&sh.qk[1][(wn + ni * 16 + fr) * ALD + kh * 32 + quad * 8];
#pragma unroll
    for (int mi = 0; mi < 4; ++mi)
#pragma unroll
      for (int ni = 0; ni < 4; ++ni)
        acc[mi * 4 + ni] = __builtin_amdgcn_mfma_f32_16x16x32_f16(
            a[mi], b[ni], acc[mi * 4 + ni], 0, 0, 0);
  }
  __syncthreads();                                           // reuse LDS as CT
#pragma unroll
  for (int mi = 0; mi < 4; ++mi)
#pragma unroll
    for (int ni = 0; ni < 4; ++ni) {
      int col = wn + ni * 16 + fr;
#pragma unroll
      for (int r = 0; r < 4; ++r) {
        int rowl = wm + mi * 16 + quad * 4 + r;
        float sc = acc[mi * 4 + ni][r] * 2.8571428571428572f;  // SCALE*16 (inputs unscaled f16)
        sc = fminf(fmaxf(sc, -127.0f), 127.0f);
        sh.ct[rowl * CTB + col] = (char)__float2int_rn(sc);
      }
    }
  __syncthreads();
  // Coalesced NT store: 16-lane quarter writes one contiguous 128 B row (2 full lines)
  char* Abase = AL + (size_t)bh * L * L;
  const int rq = lane >> 4;            // 0..3
  const int cq = (lane & 15) * 8;      // 0..120, 8 B per lane
#pragma unroll
  for (int it = 0; it < 8; ++it) {
    int row = wv * 32 + it * 4 + rq;
    uint2 v8 = *(const uint2*)&sh.ct[row * CTB + cq];
    __builtin_nontemporal_store(v8.x, (unsigned*)&Abase[(size_t)(m0 + row) * L + n0 + cq]);
    __builtin_nontemporal_store(v8.y, (unsigned*)&Abase[(size_t)(m0 + row) * L + n0 + cq + 4]);
  }
}

// ---------------- Select: int8 approx filter -> exact fp32 recompute -> softmax -> probs + PV
// One wave per row; lane owns keys (u2*64+lane)*4 + b  (u2=0..7, b=0..3).
__global__ __launch_bounds__(256) void select_kernel(const char* __restrict__ AL,
                                                     const float* __restrict__ Qp,
                                                     const float* __restrict__ Kp,
                                                     const float* __restrict__ Vp,
                                                     float* __restrict__ Probs,
                                                     float* __restrict__ Mixed) {
  __shared__ float prow[4][2048];
  __shared__ float qbuf[4][64];
  __shared__ float cbuf[4][64];
  __shared__ int ibufc[4][64];
  __shared__ float pbuf[4][32];
  __shared__ int ibuf[4][32];
  const int lane = threadIdx.x & 63;
  const int w = threadIdx.x >> 6;
  const int row = blockIdx.x * 4 + w;
  const int bh = row >> 11;
  const int q = row & 2047;
  const unsigned long long below = (lane == 63) ? 0x7fffffffffffffffull
                                                : ((1ull << lane) - 1ull);
  const unsigned* Arow = (const unsigned*)(AL + (size_t)row * 2048);

  float lg[32];
#pragma unroll
  for (int u2 = 0; u2 < 8; ++u2) {
    unsigned dw = __builtin_nontemporal_load(Arow + u2 * 64 + lane);
#pragma unroll
    for (int b = 0; b < 4; ++b)
      lg[u2 * 4 + b] = (float)((char)(dw >> (8 * b))) * QSTEP;
  }
  // zero prow early (wave-local)
#pragma unroll
  for (int u = 0; u < 32; ++u) prow[w][u * 64 + lane] = 0.f;
  // stage fp32 Q row (unscaled)
  if (lane < 16)
    *(float4*)&qbuf[w][lane * 4] = *(const float4*)&Qp[((size_t)bh * L + q) * 64 + lane * 4];

  float m = lg[0];
#pragma unroll
  for (int u = 1; u < 32; ++u) m = fmaxf(m, lg[u]);
  m = wave_fmax(m);

  // ---- T32a = 32nd-largest approx value (bit-exact on approx grid)
  float T = 0.f;
  bool found = false;
  float cut = m - 2.2f;
  float lo = 0.f, hi = m;
  bool has_lo = false;
  for (int attempt = 0; attempt < 8 && !found; ++attempt) {
    int c = 0;
#pragma unroll
    for (int u = 0; u < 32; ++u) c += (lg[u] > cut) ? 1 : 0;
    c = wave_isum(c);
    if (c < 32) {
      hi = cut;
      cut = has_lo ? 0.5f * (lo + cut) : (cut - 0.45f);
    } else if (c > 64) {
      lo = cut; has_lo = true;
      cut = 0.5f * (cut + hi);
    } else {
      int base = 0;                    // slot order arbitrary (set semantics)
#pragma unroll
      for (int u = 0; u < 32; ++u) {
        bool cd = lg[u] > cut;
        unsigned long long mk = __ballot(cd);
        if (cd) cbuf[w][base + __popcll(mk & below)] = lg[u];
        base += __popcll(mk);
      }
      lds_fence();
      float v2 = (lane < c) ? cbuf[w][lane] : -FLT_MAX;
#pragma unroll
      for (int size = 2; size <= 64; size <<= 1)
#pragma unroll
        for (int stride = size >> 1; stride; stride >>= 1) {
          float pv = __shfl_xor(v2, stride);
          bool lower = (lane & stride) == 0;
          bool asc = (lane & size) == 0;
          v2 = (lower == asc) ? fminf(v2, pv) : fmaxf(v2, pv);
        }
      T = __shfl(v2, 32);
      found = true;
    }
  }
  if (!found) {   // exact radix bisect on approx bits
    unsigned tb = 0;
    for (int bit = 31; bit >= 0; --bit) {
      unsigned cand = tb | (1u << bit);
      int c = 0;
#pragma unroll
      for (int u = 0; u < 32; ++u) c += (f2sort(lg[u]) >= cand) ? 1 : 0;
      c = wave_isum(c);
      if (c >= 32) tb = cand;
    }
    T = (tb & 0x80000000u) ? __uint_as_float(tb & 0x7fffffffu) : __uint_as_float(~tb);
  }

  // ---- candidate set: largest margin whose count fits the 64 recompute slots
  float theta = T;
  int c2 = 0;
  const float margs[5] = {0.40f, 0.25f, 0.15f, 0.08f, 0.0f};
#pragma unroll
  for (int a = 0; a < 5; ++a) {
    float th = T - margs[a];
    int c = 0;
#pragma unroll
    for (int u = 0; u < 32; ++u) c += (lg[u] >= th) ? 1 : 0;
    c = wave_isum(c);
    theta = th; c2 = c;
    if (c <= 64) break;
  }
  if (c2 > 64) c2 = 64;   // astronomically unlikely tie flood

  // rank-scatter candidate flat indices (slot order arbitrary)
  {
    int base = 0;
#pragma unroll
    for (int u = 0; u < 32; ++u) {
      bool cd = lg[u] >= theta;
      unsigned long long mk = __ballot(cd);
      if (cd) {
        int s = base + __popcll(mk & below);
        if (s < 64) ibufc[w][s] = ((u >> 2) * 64 + lane) * 4 + (u & 3);
      }
      base += __popcll(mk);
    }
  }
  lds_fence();

  // ---- exact fp32 recompute for candidates (one per lane)
  int myi = (lane < c2) ? ibufc[w][lane] : 0x7fffffff;
  float vex = -FLT_MAX;
  if (lane < c2) {
    const float4* K4 = (const float4*)(Kp + ((size_t)bh * L + myi) * 64);
    const float4* Q4 = (const float4*)&qbuf[w][0];
    float acc = 0.f;
#pragma unroll
    for (int dq = 0; dq < 16; ++dq) {
      float4 kv = K4[dq];
      float4 qv = Q4[dq];
      acc = fmaf(qv.x, kv.x, acc);
      acc = fmaf(qv.y, kv.y, acc);
      acc = fmaf(qv.z, kv.z, acc);
      acc = fmaf(qv.w, kv.w, acc);
    }
    vex = (acc * 0.125f) / 0.7f;   // matches ref: (q/8)@k then /0.7
  }

  // ---- sort 64 lanes by (value desc, index asc): key ascending
  unsigned long long key = ((unsigned long long)(~f2sort(vex)) << 32) | (unsigned)myi;
#pragma unroll
  for (int size = 2; size <= 64; size <<= 1)
#pragma unroll
    for (int stride = size >> 1; stride; stride >>= 1) {
      unsigned long long pk = __shfl_xor(key, stride);
      unsigned long long mn = key < pk ? key : pk;
      unsigned long long mx = key < pk ? pk : key;
      bool keepmin = ((lane & stride) == 0) == ((lane & size) == 0);
      key = keepmin ? mn : mx;
    }
  unsigned uv = ~(unsigned)(key >> 32);
  float vs = __uint_as_float((uv & 0x80000000u) ? (uv & 0x7fffffffu) : ~uv);
  int sidx = (int)(unsigned)(key & 0xffffffffull);

  // ---- softmax over kept 32 (lanes 0..31 sorted best-first)
  float vmax = __shfl(vs, 0);
  float e = (lane < 32) ? __expf(vs - vmax) : 0.f;
  float S = wave_fsum(e);
  float p = e / S;
  if (lane < 32) {
    pbuf[w][lane] = p;
    ibuf[w][lane] = sidx;
    prow[w][sidx] = p;
  }
  lds_fence();

  // ---- dense probs row write (zeros + 32 kept)
  float* Prow = Probs + (size_t)row * 2048;
#pragma unroll
  for (int u = 0; u < 32; ++u)
    __builtin_nontemporal_store(prow[w][u * 64 + lane], Prow + u * 64 + lane);

  // ---- sparse PV
  const float* Vb = Vp + (size_t)bh * L * 64;
  float accv = 0.f;
#pragma unroll
  for (int i = 0; i < 32; ++i)
    accv = fmaf(pbuf[w][i], Vb[(size_t)ibuf[w][i] * 64 + lane], accv);
  const int bb = bh >> 4, hh = bh & 15;
  Mixed[((size_t)(bb * 2048 + q)) * 1024 + hh * 64 + lane] = accv;
}

// ---------------- Output FC: Out[m][n] = sum_k Mixed[m][k] * Wfc[n][k]  (M=4096,N=64,K=1024)
__global__ __launch_bounds__(256) void fc_kernel(const float* __restrict__ Mx,
                                                 const float* __restrict__ Wfc,
                                                 float* __restrict__ Out) {
  __shared__ float As[32][64];
  __shared__ float Ws[64][64];
  const int t = threadIdx.x;
  const int tx = t & 15;
  const int ty = t >> 4;
  const int m0 = blockIdx.x * 32;
  float acc[2][4] = {};
  for (int k0 = 0; k0 < 1024; k0 += 64) {
    __syncthreads();
    {
      int lin = t * 8;
      int rr = lin >> 6, kk = lin & 63;
      *(float4*)&As[rr][kk] = *(const float4*)&Mx[(size_t)(m0 + rr) * 1024 + k0 + kk];
      *(float4*)&As[rr][kk + 4] = *(const float4*)&Mx[(size_t)(m0 + rr) * 1024 + k0 + kk + 4];
    }
    {
      int n = t >> 2;
      int kq = (t & 3) * 16;
#pragma unroll
      for (int u = 0; u < 4; ++u) {
        float4 wv = *(const float4*)&Wfc[(size_t)n * 1024 + k0 + kq + u * 4];
        Ws[kq + u * 4 + 0][n] = wv.x;
        Ws[kq + u * 4 + 1][n] = wv.y;
        Ws[kq + u * 4 + 2][n] = wv.z;
        Ws[kq + u * 4 + 3][n] = wv.w;
      }
    }
    __syncthreads();
#pragma unroll
    for (int kk = 0; kk < 64; ++kk) {
      float a0 = As[ty][kk], a1 = As[ty + 16][kk];
      float4 wv = *(const float4*)&Ws[kk][tx * 4];
      float wr[4] = {wv.x, wv.y, wv.z, wv.w};
#pragma unroll
      for (int j = 0; j < 4; ++j) {
        acc[0][j] = fmaf(a0, wr[j], acc[0][j]);
        acc[1][j] = fmaf(a1, wr[j], acc[1][j]);
      }
    }
  }
#pragma unroll
  for (int i = 0; i < 2; ++i) {
    int mm = m0 + ty + i * 16;
    *(float4*)&Out[(size_t)mm * 64 + tx * 4] =
        make_float4(acc[i][0], acc[i][1], acc[i][2], acc[i][3]);
  }
}

extern "C" void kernel_launch(void* const* d_in, const int* in_sizes, int n_in,
                              void* d_out, int out_size, void* d_ws, size_t ws_size,
                              hipStream_t stream) {
  const float* q    = (const float*)d_in[0];
  const float* k    = (const float*)d_in[1];
  const float* v    = (const float*)d_in[2];
  const float* w_q  = (const float*)d_in[3];
  const float* w_k  = (const float*)d_in[4];
  const float* w_v  = (const float*)d_in[5];
  const float* w_fc = (const float*)d_in[6];

  float* out = (float*)d_out;
  float* probs = out + OUT0;

  float* ws = (float*)d_ws;
  float* q_proj = ws;                          // [B][H][L][64] fp32 (UNSCALED)
  float* k_proj = ws + 4194304;
  float* v_proj = ws + 8388608;
  float* mixed  = ws + 12582912;               // [B*L][1024]
  unsigned short* qb = (unsigned short*)(ws + 16777216);   // f16(q_proj) for alogits
  unsigned short* kb = (unsigned short*)(ws + 18874368);   // f16(k_proj)
  char* al = (char*)(ws + 20971520);           // approx logits int8 [bh][i][j], 128 MB

  // fp16 hi/lo split arrays (inputs * 256), placed after AL
  unsigned short* qh  = (unsigned short*)((char*)d_ws + 234881024);  // 224 MiB
  unsigned short* ql  = qh + 4194304;
  unsigned short* kh  = ql + 4194304;
  unsigned short* kl  = kh + 4194304;
  unsigned short* wqh = kl + 4194304;
  unsigned short* wql = wqh + 1048576;
  unsigned short* wkh = wql + 1048576;
  unsigned short* wkl = wkh + 1048576;

  dim3 blk(256);
  split_kernel<<<dim3(1024, 4), blk, 0, stream>>>(q, k, w_q, w_k,
                                                  qh, ql, kh, kl, wqh, wql, wkh, wkl);
  proj_split_kernel<<<dim3(8, 32, 2), blk, 0, stream>>>(qh, ql, kh, kl,
                                                        wqh, wql, wkh, wkl,
                                                        q_proj, k_proj, qb, kb);
  proj_kernel<64, false><<<dim3(16, 32), blk, 0, stream>>>(v, w_v, v_proj, nullptr, 1.0f);
  alogits_kernel<<<dim3(16, 16, 32), blk, 0, stream>>>(qb, kb, al);
  select_kernel<<<dim3(16384), blk, 0, stream>>>(al, q_proj, k_proj, v_proj, probs, mixed);
  fc_kernel<<<dim3(128), blk, 0, stream>>>(mixed, w_fc, out);
}

// Round 3
// 855.215 us; speedup vs baseline: 1.1780x; 1.0087x over previous
//
#include <hip/hip_runtime.h>
#include <stdint.h>
#include <float.h>

// B=2, L=2048, E=1024, H=16, Dk=Dv=64, top_k=32, temperature=0.7
constexpr int L = 2048;
constexpr int H = 16;
constexpr float SCALE = 0.17857142857142858f;   // 1/(sqrt(64)*0.7)
constexpr int OUT0 = 2 * 2048 * 64;             // output floats; probs follow in d_out
constexpr float QSTEP = 0.0625f;                // int8 AL quant step (scale 16/unit)

typedef float f32x4 __attribute__((ext_vector_type(4)));
typedef short s16x8 __attribute__((ext_vector_type(8)));
typedef unsigned short u16x8 __attribute__((ext_vector_type(8)));
typedef _Float16 h16x8 __attribute__((ext_vector_type(8)));

__device__ __forceinline__ unsigned f2sort(float f) {
  unsigned u = __float_as_uint(f);
  return (u & 0x80000000u) ? ~u : (u | 0x80000000u);
}
__device__ __forceinline__ void lds_fence() {
  __asm__ __volatile__("s_waitcnt lgkmcnt(0)" ::: "memory");
}

// ---- DPP wave-64 reductions (VALU-only; ~8 cy/step vs ~120 cy for ds_swizzle shfl)
// row_shr:1/2/4/8 = 0x111/0x112/0x114/0x118, row_bcast15 = 0x142, row_bcast31 = 0x143.
// Sum: old=0, bound_ctrl=true (OOB reads 0 = identity). Max/min: old=x, bc=false (OOB -> x).
__device__ __forceinline__ int wave_isum_dpp(int x) {
#define DPP_ADDI(CTRL) x += __builtin_amdgcn_update_dpp(0, x, CTRL, 0xf, 0xf, true);
  DPP_ADDI(0x111) DPP_ADDI(0x112) DPP_ADDI(0x114)
  DPP_ADDI(0x118) DPP_ADDI(0x142) DPP_ADDI(0x143)
#undef DPP_ADDI
  return __builtin_amdgcn_readlane(x, 63);
}
__device__ __forceinline__ float wave_fsum_dpp(float x) {
  int xi = __builtin_bit_cast(int, x);
#define DPP_ADDF(CTRL)                                                      \
  {                                                                         \
    int _s = __builtin_amdgcn_update_dpp(0, xi, CTRL, 0xf, 0xf, true);      \
    x = x + __builtin_bit_cast(float, _s);                                  \
    xi = __builtin_bit_cast(int, x);                                        \
  }
  DPP_ADDF(0x111) DPP_ADDF(0x112) DPP_ADDF(0x114)
  DPP_ADDF(0x118) DPP_ADDF(0x142) DPP_ADDF(0x143)
#undef DPP_ADDF
  return __builtin_bit_cast(float, __builtin_amdgcn_readlane(xi, 63));
}
__device__ __forceinline__ float wave_fmax_dpp(float x) {
  int xi = __builtin_bit_cast(int, x);
#define DPP_MAXF(CTRL)                                                      \
  {                                                                         \
    int _s = __builtin_amdgcn_update_dpp(xi, xi, CTRL, 0xf, 0xf, false);    \
    x = fmaxf(x, __builtin_bit_cast(float, _s));                            \
    xi = __builtin_bit_cast(int, x);                                        \
  }
  DPP_MAXF(0x111) DPP_MAXF(0x112) DPP_MAXF(0x114)
  DPP_MAXF(0x118) DPP_MAXF(0x142) DPP_MAXF(0x143)
#undef DPP_MAXF
  return __builtin_bit_cast(float, __builtin_amdgcn_readlane(xi, 63));
}
__device__ __forceinline__ int wave_imin_dpp(int x) {
#define DPP_MINI(CTRL)                                                      \
  {                                                                         \
    int _s = __builtin_amdgcn_update_dpp(x, x, CTRL, 0xf, 0xf, false);      \
    x = min(x, _s);                                                         \
  }
  DPP_MINI(0x111) DPP_MINI(0x112) DPP_MINI(0x114)
  DPP_MINI(0x118) DPP_MINI(0x142) DPP_MINI(0x143)
#undef DPP_MINI
  return __builtin_amdgcn_readlane(x, 63);
}

// global -> LDS direct (16B per lane). Wrapper handles addrspace casts.
__device__ __forceinline__ void gload_lds16(const void* g, void* l) {
  __builtin_amdgcn_global_load_lds((const __attribute__((address_space(1))) void*)g,
                                   (__attribute__((address_space(3))) void*)l, 16, 0, 0);
}

// ---------------- fp32 -> fp16 hi/lo split (inputs pre-scaled by 256 to keep lo normal)
__global__ __launch_bounds__(256) void split_kernel(
    const float* __restrict__ q, const float* __restrict__ k,
    const float* __restrict__ wq, const float* __restrict__ wk,
    unsigned short* __restrict__ qh, unsigned short* __restrict__ ql,
    unsigned short* __restrict__ kh, unsigned short* __restrict__ kl,
    unsigned short* __restrict__ wqh, unsigned short* __restrict__ wql,
    unsigned short* __restrict__ wkh, unsigned short* __restrict__ wkl) {
  const int y = blockIdx.y;
  const float* src = (y == 0) ? q : (y == 1) ? k : (y == 2) ? wq : wk;
  unsigned short* dh = (y == 0) ? qh : (y == 1) ? kh : (y == 2) ? wqh : wkh;
  unsigned short* dl = (y == 0) ? ql : (y == 1) ? kl : (y == 2) ? wql : wkl;
  const int n = (y < 2) ? (4096 * 1024) : (1024 * 1024);
  int idx = (blockIdx.x * 256 + threadIdx.x) * 4;
  const int stride = gridDim.x * 256 * 4;
  for (; idx < n; idx += stride) {
    float4 v = *(const float4*)(src + idx);
    float xs[4] = {v.x, v.y, v.z, v.w};
    unsigned short hs[4], ls[4];
#pragma unroll
    for (int i = 0; i < 4; ++i) {
      float x = xs[i] * 256.0f;
      _Float16 hh = (_Float16)x;
      float r = x - (float)hh;
      _Float16 ll = (_Float16)r;
      hs[i] = __builtin_bit_cast(unsigned short, hh);
      ls[i] = __builtin_bit_cast(unsigned short, ll);
    }
    *(ushort4*)(dh + idx) = make_ushort4(hs[0], hs[1], hs[2], hs[3]);
    *(ushort4*)(dl + idx) = make_ushort4(ls[0], ls[1], ls[2], ls[3]);
  }
}

// ---------------- Projection GEMM via fp16 hi/lo split MFMA (fp32-grade accuracy)
__global__ __launch_bounds__(256, 2) void proj_split_kernel(
    const unsigned short* __restrict__ QH, const unsigned short* __restrict__ QL,
    const unsigned short* __restrict__ KH, const unsigned short* __restrict__ KL,
    const unsigned short* __restrict__ WQH, const unsigned short* __restrict__ WQL,
    const unsigned short* __restrict__ WKH, const unsigned short* __restrict__ WKL,
    float* __restrict__ QP, float* __restrict__ KP,
    unsigned short* __restrict__ Q16, unsigned short* __restrict__ K16) {
  __shared__ unsigned short sh[4][128 * 64];   // Xh, Xl, Wh, Wl : 64 KiB
  const int t = threadIdx.x;
  const int z = blockIdx.z;
  const int m0 = blockIdx.y * 128;
  const int n0 = blockIdx.x * 128;
  const unsigned short* xh = z ? KH : QH;
  const unsigned short* xl = z ? KL : QL;
  const unsigned short* wh = z ? WKH : WQH;
  const unsigned short* wl = z ? WKL : WQL;
  float* Y = z ? KP : QP;
  unsigned short* Y16 = z ? K16 : Q16;
  const unsigned short* mats[4] = {xh + (size_t)m0 * 1024, xl + (size_t)m0 * 1024,
                                   wh + (size_t)n0 * 1024, wl + (size_t)n0 * 1024};
  const int wv = t >> 6, lane = t & 63;
  const int wm = (wv & 1) * 64, wn = (wv >> 1) * 64;
  const int fr = lane & 15, quad = lane >> 4;
  f32x4 acc[16];
#pragma unroll
  for (int i = 0; i < 16; ++i) acc[i] = (f32x4){0.f, 0.f, 0.f, 0.f};

#define STAGE(cc)                                                              \
  {                                                                            \
    const int k0s = (cc) * 64;                                                 \
    _Pragma("unroll") for (int j = 0; j < 16; ++j) {                           \
      const int mat = j >> 2;                                                  \
      const int idx = (j & 3) * 256 + t;                                       \
      const int r = idx >> 3, p = idx & 7;                                     \
      const int sb = p ^ (r & 7);                                              \
      gload_lds16(mats[mat] + (size_t)r * 1024 + k0s + sb * 8, &sh[mat][idx * 8]); \
    }                                                                          \
  }

  STAGE(0);
  for (int c = 0; c < 16; ++c) {
    __syncthreads();                   // vmcnt(0): stage(c) landed in LDS
    h16x8 ah[2][4], alv[2][4], bh[2][4], blv[2][4];
#pragma unroll
    for (int kh2 = 0; kh2 < 2; ++kh2) {
#pragma unroll
      for (int mi = 0; mi < 4; ++mi) {
        int row = wm + mi * 16 + fr;
        int pp = (kh2 * 4 + quad) ^ (row & 7);
        ah[kh2][mi]  = *(const h16x8*)&sh[0][row * 64 + pp * 8];
        alv[kh2][mi] = *(const h16x8*)&sh[1][row * 64 + pp * 8];
      }
#pragma unroll
      for (int ni = 0; ni < 4; ++ni) {
        int row = wn + ni * 16 + fr;
        int pp = (kh2 * 4 + quad) ^ (row & 7);
        bh[kh2][ni]  = *(const h16x8*)&sh[2][row * 64 + pp * 8];
        blv[kh2][ni] = *(const h16x8*)&sh[3][row * 64 + pp * 8];
      }
    }
    __syncthreads();                   // all waves' ds_reads done -> LDS reusable
    if (c < 15) STAGE(c + 1);          // prefetch next chunk under the MFMAs
#pragma unroll
    for (int kh2 = 0; kh2 < 2; ++kh2)
#pragma unroll
      for (int mi = 0; mi < 4; ++mi)
#pragma unroll
        for (int ni = 0; ni < 4; ++ni) {
          acc[mi * 4 + ni] = __builtin_amdgcn_mfma_f32_16x16x32_f16(ah[kh2][mi], bh[kh2][ni], acc[mi * 4 + ni], 0, 0, 0);
          acc[mi * 4 + ni] = __builtin_amdgcn_mfma_f32_16x16x32_f16(ah[kh2][mi], blv[kh2][ni], acc[mi * 4 + ni], 0, 0, 0);
          acc[mi * 4 + ni] = __builtin_amdgcn_mfma_f32_16x16x32_f16(alv[kh2][mi], bh[kh2][ni], acc[mi * 4 + ni], 0, 0, 0);
        }
  }
#undef STAGE
#pragma unroll
  for (int mi = 0; mi < 4; ++mi)
#pragma unroll
    for (int ni = 0; ni < 4; ++ni) {
      int col = n0 + wn + ni * 16 + fr;
      int h = col >> 6, d = col & 63;
#pragma unroll
      for (int r = 0; r < 4; ++r) {
        int m = m0 + wm + mi * 16 + quad * 4 + r;
        int b = m >> 11, l = m & 2047;
        size_t off = (((size_t)b * H + h) * L + l) * 64 + d;
        float val = acc[mi * 4 + ni][r] * (1.0f / 65536.0f);
        Y[off] = val;
        _Float16 hf = (_Float16)val;
        Y16[off] = __builtin_bit_cast(unsigned short, hf);
      }
    }
}

// ---------------- Projection GEMM (fp32 scalar path — kept for V, K=64 only)
template <int K, bool EMIT>
__global__ __launch_bounds__(256) void proj_kernel(const float* __restrict__ X,
                                                   const float* __restrict__ W,
                                                   float* __restrict__ Y,
                                                   unsigned short* __restrict__ Yb,
                                                   float bscale) {
  __shared__ float As[16][128];
  __shared__ float Bs[16][64];
  const int t = threadIdx.x;
  const int tx = t & 15;
  const int ty = t >> 4;
  const int m0 = blockIdx.y * 128;
  const int n0 = blockIdx.x * 64;
  const int ar = t >> 1, ac = (t & 1) * 8;
  const int br = t >> 2, bc = (t & 3) * 4;
  const float* xg = X + (size_t)(m0 + ar) * K + ac;
  const float* wg = W + (size_t)(n0 + br) * K + bc;
  float acc[8][4] = {};
  for (int k0 = 0; k0 < K; k0 += 16) {
    float4 a0 = *(const float4*)(xg + k0);
    float4 a1 = *(const float4*)(xg + k0 + 4);
    float4 b0 = *(const float4*)(wg + k0);
    __syncthreads();
    As[ac + 0][ar] = a0.x; As[ac + 1][ar] = a0.y; As[ac + 2][ar] = a0.z; As[ac + 3][ar] = a0.w;
    As[ac + 4][ar] = a1.x; As[ac + 5][ar] = a1.y; As[ac + 6][ar] = a1.z; As[ac + 7][ar] = a1.w;
    Bs[bc + 0][br] = b0.x; Bs[bc + 1][br] = b0.y; Bs[bc + 2][br] = b0.z; Bs[bc + 3][br] = b0.w;
    __syncthreads();
#pragma unroll
    for (int kk = 0; kk < 16; ++kk) {
      float4 av0 = *(const float4*)&As[kk][ty * 8];
      float4 av1 = *(const float4*)&As[kk][ty * 8 + 4];
      float4 bv = *(const float4*)&Bs[kk][tx * 4];
      float ar8[8] = {av0.x, av0.y, av0.z, av0.w, av1.x, av1.y, av1.z, av1.w};
      float br4[4] = {bv.x, bv.y, bv.z, bv.w};
#pragma unroll
      for (int i = 0; i < 8; ++i)
#pragma unroll
        for (int j = 0; j < 4; ++j) acc[i][j] = fmaf(ar8[i], br4[j], acc[i][j]);
    }
  }
  const int n = n0 + tx * 4;
  const int h = n >> 6, d = n & 63;
#pragma unroll
  for (int i = 0; i < 8; ++i) {
    int mm = m0 + ty * 8 + i;
    int b = mm >> 11, l = mm & 2047;
    size_t off = (((size_t)b * H + h) * L + l) * 64 + d;
    *(float4*)&Y[off] = make_float4(acc[i][0], acc[i][1], acc[i][2], acc[i][3]);
  }
}

// ---------------- Approx logits, f16 MFMA -> int8 AL (quant = logit*16, clamp +-127)
constexpr int ALD = 72;    // padded LDS stride (f16 units) for frag reads
constexpr int CTB = 136;   // int8 CT stride in bytes (8-aligned, non-pow2)

__global__ __launch_bounds__(256) void alogits_kernel(const unsigned short* __restrict__ Qb,
                                                      const unsigned short* __restrict__ Kb,
                                                      char* __restrict__ AL) {
  __shared__ union {
    unsigned short qk[2][128 * ALD];   // 36864 B
    char ct[128 * CTB];                // 17408 B
  } sh;
  const int t = threadIdx.x;
  const int bh = blockIdx.z;
  const int m0 = blockIdx.y * 128, n0 = blockIdx.x * 128;
  const unsigned short* Qg = Qb + (size_t)bh * L * 64 + (size_t)m0 * 64;
  const unsigned short* Kg = Kb + (size_t)bh * L * 64 + (size_t)n0 * 64;
#pragma unroll
  for (int i = 0; i < 4; ++i) {
    int blk = t * 4 + i;               // 0..1023 : 128 rows x 8 blocks(16B)
    int r = blk >> 3, lb = blk & 7;
    *(u16x8*)&sh.qk[0][r * ALD + lb * 8] = *(const u16x8*)&Qg[r * 64 + lb * 8];
    *(u16x8*)&sh.qk[1][r * ALD + lb * 8] = *(const u16x8*)&Kg[r * 64 + lb * 8];
  }
  __syncthreads();
  const int wv = t >> 6, lane = t & 63;
  const int wm = (wv & 1) * 64, wn = (wv >> 1) * 64;
  const int fr = lane & 15, quad = lane >> 4;
  f32x4 acc[16];
#pragma unroll
  for (int i = 0; i < 16; ++i) acc[i] = (f32x4){0.f, 0.f, 0.f, 0.f};
#pragma unroll
  for (int kh = 0; kh < 2; ++kh) {
    h16x8 a[4], b[4];
#pragma unroll
    for (int mi = 0; mi < 4; ++mi)
      a[mi] = *(const h16x8*)&sh.qk[0][(wm + mi * 16 + fr) * ALD + kh * 32 + quad * 8];
#pragma unroll
    for (int ni = 0; ni < 4; ++ni)
      b[ni] = *(const h16x8*)&sh.qk[1][(wn + ni * 16 + fr) * ALD + kh * 32 + quad * 8];
#pragma unroll
    for (int mi = 0; mi < 4; ++mi)
#pragma unroll
      for (int ni = 0; ni < 4; ++ni)
        acc[mi * 4 + ni] = __builtin_amdgcn_mfma_f32_16x16x32_f16(
            a[mi], b[ni], acc[mi * 4 + ni], 0, 0, 0);
  }
  __syncthreads();                                           // reuse LDS as CT
#pragma unroll
  for (int mi = 0; mi < 4; ++mi)
#pragma unroll
    for (int ni = 0; ni < 4; ++ni) {
      int col = wn + ni * 16 + fr;
#pragma unroll
      for (int r = 0; r < 4; ++r) {
        int rowl = wm + mi * 16 + quad * 4 + r;
        float sc = acc[mi * 4 + ni][r] * 2.8571428571428572f;  // SCALE*16 (inputs unscaled f16)
        sc = fminf(fmaxf(sc, -127.0f), 127.0f);
        sh.ct[rowl * CTB + col] = (char)__float2int_rn(sc);
      }
    }
  __syncthreads();
  char* Abase = AL + (size_t)bh * L * L;
  const int rq = lane >> 4;            // 0..3
  const int cq = (lane & 15) * 8;      // 0..120, 8 B per lane
#pragma unroll
  for (int it = 0; it < 8; ++it) {
    int row = wv * 32 + it * 4 + rq;
    uint2 v8 = *(const uint2*)&sh.ct[row * CTB + cq];
    __builtin_nontemporal_store(v8.x, (unsigned*)&Abase[(size_t)(m0 + row) * L + n0 + cq]);
    __builtin_nontemporal_store(v8.y, (unsigned*)&Abase[(size_t)(m0 + row) * L + n0 + cq + 4]);
  }
}

// ---------------- Select: int8 approx filter -> exact fp32 recompute -> softmax -> probs + PV
// One wave per row; lane owns keys (u2*64+lane)*4 + b  (u2=0..7, b=0..3).
// All wave reductions via DPP (VALU); thresholds on the int8 grid (exact);
// top-32-of-candidates via ballot bisection on f2sort bits (exact, idx-asc ties).
__global__ __launch_bounds__(256) void select_kernel(const char* __restrict__ AL,
                                                     const float* __restrict__ Qp,
                                                     const float* __restrict__ Kp,
                                                     const float* __restrict__ Vp,
                                                     float* __restrict__ Probs,
                                                     float* __restrict__ Mixed) {
  __shared__ float prow[4][2048];
  __shared__ float qbuf[4][64];
  __shared__ int ibufc[4][64];
  __shared__ float pbuf[4][32];
  __shared__ int ibuf[4][32];
  const int lane = threadIdx.x & 63;
  const int w = threadIdx.x >> 6;
  const int row = blockIdx.x * 4 + w;
  const int bh = row >> 11;
  const int q = row & 2047;
  const unsigned long long below = (lane == 63) ? 0x7fffffffffffffffull
                                                : ((1ull << lane) - 1ull);
  const unsigned* Arow = (const unsigned*)(AL + (size_t)row * 2048);

  int li[32];
#pragma unroll
  for (int u2 = 0; u2 < 8; ++u2) {
    unsigned dw = __builtin_nontemporal_load(Arow + u2 * 64 + lane);
#pragma unroll
    for (int b = 0; b < 4; ++b)
      li[u2 * 4 + b] = (int)((char)(dw >> (8 * b)));
  }
  // zero prow early (wave-local)
#pragma unroll
  for (int u = 0; u < 32; ++u) prow[w][u * 64 + lane] = 0.f;
  // stage fp32 Q row (unscaled)
  if (lane < 16)
    *(float4*)&qbuf[w][lane * 4] = *(const float4*)&Qp[((size_t)bh * L + q) * 64 + lane * 4];

  // ---- exact 32nd-largest approx value on the int8 grid: 8-step bisection.
  // invariant: count(li >= tlo) >= 32, count(li >= thi) < 32
  int tlo = -128, thi = 128;
#pragma unroll
  for (int it = 0; it < 8; ++it) {
    int mid = (tlo + thi) >> 1;
    int c = 0;
#pragma unroll
    for (int u = 0; u < 32; ++u) c += (li[u] >= mid) ? 1 : 0;
    c = wave_isum_dpp(c);
    if (c >= 32) tlo = mid; else thi = mid;
  }
  const int t32 = tlo;   // exact 32nd-largest (int units)

  // ---- candidate set: largest margin whose count fits the 64 recompute slots
  // int margins {6,4,2,1,0} are bit-exact equivalents of {0.40f,0.25f,0.15f,0.08f,0}
  int theta = t32;
  int c2 = 0;
  const int margs[5] = {6, 4, 2, 1, 0};
#pragma unroll
  for (int a = 0; a < 5; ++a) {
    int th = t32 - margs[a];
    int c = 0;
#pragma unroll
    for (int u = 0; u < 32; ++u) c += (li[u] >= th) ? 1 : 0;
    c = wave_isum_dpp(c);
    theta = th; c2 = c;
    if (c <= 64) break;
  }
  if (c2 > 64) c2 = 64;   // astronomically unlikely tie flood

  // rank-scatter candidate flat indices (slot order arbitrary)
  {
    int base = 0;
#pragma unroll
    for (int u = 0; u < 32; ++u) {
      bool cd = li[u] >= theta;
      unsigned long long mk = __ballot(cd);
      if (cd) {
        int s = base + __popcll(mk & below);
        if (s < 64) ibufc[w][s] = ((u >> 2) * 64 + lane) * 4 + (u & 3);
      }
      base += __popcll(mk);
    }
  }
  lds_fence();

  // ---- exact fp32 recompute for candidates (one per lane)
  int myi = (lane < c2) ? ibufc[w][lane] : 0x7fffffff;
  float vex = -FLT_MAX;
  if (lane < c2) {
    const float4* K4 = (const float4*)(Kp + ((size_t)bh * L + myi) * 64);
    const float4* Q4 = (const float4*)&qbuf[w][0];
    float acc = 0.f;
#pragma unroll
    for (int dq = 0; dq < 16; ++dq) {
      float4 kv = K4[dq];
      float4 qv = Q4[dq];
      acc = fmaf(qv.x, kv.x, acc);
      acc = fmaf(qv.y, kv.y, acc);
      acc = fmaf(qv.z, kv.z, acc);
      acc = fmaf(qv.w, kv.w, acc);
    }
    vex = (acc * 0.125f) / 0.7f;   // matches ref: (q/8)@k then /0.7
  }

  // ---- top-32 selection: bisection on sort-order bits (exact), idx-asc tie-break
  const unsigned sk = f2sort(vex);
  unsigned tb = 0;
#pragma unroll
  for (int bit = 31; bit >= 0; --bit) {
    unsigned cand = tb | (1u << bit);
    int cnt = (int)__popcll(__ballot(sk >= cand));
    if (cnt >= 32) tb = cand;
  }
  // tb == 32nd-largest sk. count(sk > tb) < 32 <= count(sk >= tb).
  bool kept = sk > tb;
  {
    int cnt_gt = (int)__popcll(__ballot(kept));
    int need = 32 - cnt_gt;            // >= 1
    unsigned long long tiem = __ballot(sk == tb);
    if ((int)__popcll(tiem) <= need) {
      kept = kept || (sk == tb);       // all ties fit (common case)
    } else {                           // rare: pick `need` smallest indices among ties
      bool isT = (sk == tb);
      for (int r = 0; r < need; ++r) {
        int mi = wave_imin_dpp(isT ? myi : 0x7fffffff);
        if (isT && myi == mi) { kept = true; isT = false; }
      }
    }
  }

  // ---- softmax over kept 32
  float vmax = wave_fmax_dpp(vex);     // global max is kept top-1
  float e = kept ? __expf(vex - vmax) : 0.f;
  float S = wave_fsum_dpp(e);
  float p = e / S;
  {
    unsigned long long km = __ballot(kept);
    int slot = (int)__popcll(km & below);
    if (kept) {
      pbuf[w][slot] = p;
      ibuf[w][slot] = myi;
      prow[w][myi] = p;
    }
  }
  lds_fence();

  // ---- dense probs row write (zeros + 32 kept)
  float* Prow = Probs + (size_t)row * 2048;
#pragma unroll
  for (int u = 0; u < 32; ++u)
    __builtin_nontemporal_store(prow[w][u * 64 + lane], Prow + u * 64 + lane);

  // ---- sparse PV
  const float* Vb = Vp + (size_t)bh * L * 64;
  float accv = 0.f;
#pragma unroll
  for (int i = 0; i < 32; ++i)
    accv = fmaf(pbuf[w][i], Vb[(size_t)ibuf[w][i] * 64 + lane], accv);
  const int bb = bh >> 4, hh = bh & 15;
  Mixed[((size_t)(bb * 2048 + q)) * 1024 + hh * 64 + lane] = accv;
}

// ---------------- Output FC: Out[m][n] = sum_k Mixed[m][k] * Wfc[n][k]  (M=4096,N=64,K=1024)
__global__ __launch_bounds__(256) void fc_kernel(const float* __restrict__ Mx,
                                                 const float* __restrict__ Wfc,
                                                 float* __restrict__ Out) {
  __shared__ float As[32][64];
  __shared__ float Ws[64][64];
  const int t = threadIdx.x;
  const int tx = t & 15;
  const int ty = t >> 4;
  const int m0 = blockIdx.x * 32;
  float acc[2][4] = {};
  for (int k0 = 0; k0 < 1024; k0 += 64) {
    __syncthreads();
    {
      int lin = t * 8;
      int rr = lin >> 6, kk = lin & 63;
      *(float4*)&As[rr][kk] = *(const float4*)&Mx[(size_t)(m0 + rr) * 1024 + k0 + kk];
      *(float4*)&As[rr][kk + 4] = *(const float4*)&Mx[(size_t)(m0 + rr) * 1024 + k0 + kk + 4];
    }
    {
      int n = t >> 2;
      int kq = (t & 3) * 16;
#pragma unroll
      for (int u = 0; u < 4; ++u) {
        float4 wv = *(const float4*)&Wfc[(size_t)n * 1024 + k0 + kq + u * 4];
        Ws[kq + u * 4 + 0][n] = wv.x;
        Ws[kq + u * 4 + 1][n] = wv.y;
        Ws[kq + u * 4 + 2][n] = wv.z;
        Ws[kq + u * 4 + 3][n] = wv.w;
      }
    }
    __syncthreads();
#pragma unroll
    for (int kk = 0; kk < 64; ++kk) {
      float a0 = As[ty][kk], a1 = As[ty + 16][kk];
      float4 wv = *(const float4*)&Ws[kk][tx * 4];
      float wr[4] = {wv.x, wv.y, wv.z, wv.w};
#pragma unroll
      for (int j = 0; j < 4; ++j) {
        acc[0][j] = fmaf(a0, wr[j], acc[0][j]);
        acc[1][j] = fmaf(a1, wr[j], acc[1][j]);
      }
    }
  }
#pragma unroll
  for (int i = 0; i < 2; ++i) {
    int mm = m0 + ty + i * 16;
    *(float4*)&Out[(size_t)mm * 64 + tx * 4] =
        make_float4(acc[i][0], acc[i][1], acc[i][2], acc[i][3]);
  }
}

extern "C" void kernel_launch(void* const* d_in, const int* in_sizes, int n_in,
                              void* d_out, int out_size, void* d_ws, size_t ws_size,
                              hipStream_t stream) {
  const float* q    = (const float*)d_in[0];
  const float* k    = (const float*)d_in[1];
  const float* v    = (const float*)d_in[2];
  const float* w_q  = (const float*)d_in[3];
  const float* w_k  = (const float*)d_in[4];
  const float* w_v  = (const float*)d_in[5];
  const float* w_fc = (const float*)d_in[6];

  float* out = (float*)d_out;
  float* probs = out + OUT0;

  float* ws = (float*)d_ws;
  float* q_proj = ws;                          // [B][H][L][64] fp32 (UNSCALED)
  float* k_proj = ws + 4194304;
  float* v_proj = ws + 8388608;
  float* mixed  = ws + 12582912;               // [B*L][1024]
  unsigned short* qb = (unsigned short*)(ws + 16777216);   // f16(q_proj) for alogits
  unsigned short* kb = (unsigned short*)(ws + 18874368);   // f16(k_proj)
  char* al = (char*)(ws + 20971520);           // approx logits int8 [bh][i][j], 128 MB

  // fp16 hi/lo split arrays (inputs * 256), placed after AL
  unsigned short* qh  = (unsigned short*)((char*)d_ws + 234881024);  // 224 MiB
  unsigned short* ql  = qh + 4194304;
  unsigned short* kh  = ql + 4194304;
  unsigned short* kl  = kh + 4194304;
  unsigned short* wqh = kl + 4194304;
  unsigned short* wql = wqh + 1048576;
  unsigned short* wkh = wql + 1048576;
  unsigned short* wkl = wkh + 1048576;

  dim3 blk(256);
  split_kernel<<<dim3(1024, 4), blk, 0, stream>>>(q, k, w_q, w_k,
                                                  qh, ql, kh, kl, wqh, wql, wkh, wkl);
  proj_split_kernel<<<dim3(8, 32, 2), blk, 0, stream>>>(qh, ql, kh, kl,
                                                        wqh, wql, wkh, wkl,
                                                        q_proj, k_proj, qb, kb);
  proj_kernel<64, false><<<dim3(16, 32), blk, 0, stream>>>(v, w_v, v_proj, nullptr, 1.0f);
  alogits_kernel<<<dim3(16, 16, 32), blk, 0, stream>>>(qb, kb, al);
  select_kernel<<<dim3(16384), blk, 0, stream>>>(al, q_proj, k_proj, v_proj, probs, mixed);
  fc_kernel<<<dim3(128), blk, 0, stream>>>(mixed, w_fc, out);
}

// Round 4
// 853.879 us; speedup vs baseline: 1.1798x; 1.0016x over previous
//
#include <hip/hip_runtime.h>
#include <stdint.h>
#include <float.h>

// B=2, L=2048, E=1024, H=16, Dk=Dv=64, top_k=32, temperature=0.7
constexpr int L = 2048;
constexpr int H = 16;
constexpr float SCALE = 0.17857142857142858f;   // 1/(sqrt(64)*0.7)
constexpr int OUT0 = 2 * 2048 * 64;             // output floats; probs follow in d_out
constexpr float QSTEP = 0.0625f;                // int8 AL quant step (scale 16/unit)

typedef float f32x4 __attribute__((ext_vector_type(4)));
typedef short s16x8 __attribute__((ext_vector_type(8)));
typedef unsigned short u16x8 __attribute__((ext_vector_type(8)));
typedef _Float16 h16x8 __attribute__((ext_vector_type(8)));

__device__ __forceinline__ unsigned f2sort(float f) {
  unsigned u = __float_as_uint(f);
  return (u & 0x80000000u) ? ~u : (u | 0x80000000u);
}
__device__ __forceinline__ void lds_fence() {
  __asm__ __volatile__("s_waitcnt lgkmcnt(0)" ::: "memory");
}

// ---- DPP wave-64 reductions (VALU-only)
__device__ __forceinline__ int wave_isum_dpp(int x) {
#define DPP_ADDI(CTRL) x += __builtin_amdgcn_update_dpp(0, x, CTRL, 0xf, 0xf, true);
  DPP_ADDI(0x111) DPP_ADDI(0x112) DPP_ADDI(0x114)
  DPP_ADDI(0x118) DPP_ADDI(0x142) DPP_ADDI(0x143)
#undef DPP_ADDI
  return __builtin_amdgcn_readlane(x, 63);
}
__device__ __forceinline__ float wave_fsum_dpp(float x) {
  int xi = __builtin_bit_cast(int, x);
#define DPP_ADDF(CTRL)                                                      \
  {                                                                         \
    int _s = __builtin_amdgcn_update_dpp(0, xi, CTRL, 0xf, 0xf, true);      \
    x = x + __builtin_bit_cast(float, _s);                                  \
    xi = __builtin_bit_cast(int, x);                                        \
  }
  DPP_ADDF(0x111) DPP_ADDF(0x112) DPP_ADDF(0x114)
  DPP_ADDF(0x118) DPP_ADDF(0x142) DPP_ADDF(0x143)
#undef DPP_ADDF
  return __builtin_bit_cast(float, __builtin_amdgcn_readlane(xi, 63));
}
__device__ __forceinline__ float wave_fmax_dpp(float x) {
  int xi = __builtin_bit_cast(int, x);
#define DPP_MAXF(CTRL)                                                      \
  {                                                                         \
    int _s = __builtin_amdgcn_update_dpp(xi, xi, CTRL, 0xf, 0xf, false);    \
    x = fmaxf(x, __builtin_bit_cast(float, _s));                            \
    xi = __builtin_bit_cast(int, x);                                        \
  }
  DPP_MAXF(0x111) DPP_MAXF(0x112) DPP_MAXF(0x114)
  DPP_MAXF(0x118) DPP_MAXF(0x142) DPP_MAXF(0x143)
#undef DPP_MAXF
  return __builtin_bit_cast(float, __builtin_amdgcn_readlane(xi, 63));
}
__device__ __forceinline__ int wave_imin_dpp(int x) {
#define DPP_MINI(CTRL)                                                      \
  {                                                                         \
    int _s = __builtin_amdgcn_update_dpp(x, x, CTRL, 0xf, 0xf, false);      \
    x = min(x, _s);                                                         \
  }
  DPP_MINI(0x111) DPP_MINI(0x112) DPP_MINI(0x114)
  DPP_MINI(0x118) DPP_MINI(0x142) DPP_MINI(0x143)
#undef DPP_MINI
  return __builtin_amdgcn_readlane(x, 63);
}

// global -> LDS direct (16B per lane). Wrapper handles addrspace casts.
__device__ __forceinline__ void gload_lds16(const void* g, void* l) {
  __builtin_amdgcn_global_load_lds((const __attribute__((address_space(1))) void*)g,
                                   (__attribute__((address_space(3))) void*)l, 16, 0, 0);
}

// ---------------- fp32 -> fp16 hi/lo split (inputs pre-scaled by 256 to keep lo normal)
__global__ __launch_bounds__(256) void split_kernel(
    const float* __restrict__ q, const float* __restrict__ k,
    const float* __restrict__ wq, const float* __restrict__ wk,
    unsigned short* __restrict__ qh, unsigned short* __restrict__ ql,
    unsigned short* __restrict__ kh, unsigned short* __restrict__ kl,
    unsigned short* __restrict__ wqh, unsigned short* __restrict__ wql,
    unsigned short* __restrict__ wkh, unsigned short* __restrict__ wkl) {
  const int y = blockIdx.y;
  const float* src = (y == 0) ? q : (y == 1) ? k : (y == 2) ? wq : wk;
  unsigned short* dh = (y == 0) ? qh : (y == 1) ? kh : (y == 2) ? wqh : wkh;
  unsigned short* dl = (y == 0) ? ql : (y == 1) ? kl : (y == 2) ? wql : wkl;
  const int n = (y < 2) ? (4096 * 1024) : (1024 * 1024);
  int idx = (blockIdx.x * 256 + threadIdx.x) * 4;
  const int stride = gridDim.x * 256 * 4;
  for (; idx < n; idx += stride) {
    float4 v = *(const float4*)(src + idx);
    float xs[4] = {v.x, v.y, v.z, v.w};
    unsigned short hs[4], ls[4];
#pragma unroll
    for (int i = 0; i < 4; ++i) {
      float x = xs[i] * 256.0f;
      _Float16 hh = (_Float16)x;
      float r = x - (float)hh;
      _Float16 ll = (_Float16)r;
      hs[i] = __builtin_bit_cast(unsigned short, hh);
      ls[i] = __builtin_bit_cast(unsigned short, ll);
    }
    *(ushort4*)(dh + idx) = make_ushort4(hs[0], hs[1], hs[2], hs[3]);
    *(ushort4*)(dl + idx) = make_ushort4(ls[0], ls[1], ls[2], ls[3]);
  }
}

// ---------------- Projection GEMM via fp16 hi/lo split MFMA (fp32-grade accuracy)
__global__ __launch_bounds__(256, 2) void proj_split_kernel(
    const unsigned short* __restrict__ QH, const unsigned short* __restrict__ QL,
    const unsigned short* __restrict__ KH, const unsigned short* __restrict__ KL,
    const unsigned short* __restrict__ WQH, const unsigned short* __restrict__ WQL,
    const unsigned short* __restrict__ WKH, const unsigned short* __restrict__ WKL,
    float* __restrict__ QP, float* __restrict__ KP,
    unsigned short* __restrict__ Q16, unsigned short* __restrict__ K16) {
  __shared__ unsigned short sh[4][128 * 64];   // Xh, Xl, Wh, Wl : 64 KiB
  const int t = threadIdx.x;
  const int z = blockIdx.z;
  const int m0 = blockIdx.y * 128;
  const int n0 = blockIdx.x * 128;
  const unsigned short* xh = z ? KH : QH;
  const unsigned short* xl = z ? KL : QL;
  const unsigned short* wh = z ? WKH : WQH;
  const unsigned short* wl = z ? WKL : WQL;
  float* Y = z ? KP : QP;
  unsigned short* Y16 = z ? K16 : Q16;
  const unsigned short* mats[4] = {xh + (size_t)m0 * 1024, xl + (size_t)m0 * 1024,
                                   wh + (size_t)n0 * 1024, wl + (size_t)n0 * 1024};
  const int wv = t >> 6, lane = t & 63;
  const int wm = (wv & 1) * 64, wn = (wv >> 1) * 64;
  const int fr = lane & 15, quad = lane >> 4;
  f32x4 acc[16];
#pragma unroll
  for (int i = 0; i < 16; ++i) acc[i] = (f32x4){0.f, 0.f, 0.f, 0.f};

#define STAGE(cc)                                                              \
  {                                                                            \
    const int k0s = (cc) * 64;                                                 \
    _Pragma("unroll") for (int j = 0; j < 16; ++j) {                           \
      const int mat = j >> 2;                                                  \
      const int idx = (j & 3) * 256 + t;                                       \
      const int r = idx >> 3, p = idx & 7;                                     \
      const int sb = p ^ (r & 7);                                              \
      gload_lds16(mats[mat] + (size_t)r * 1024 + k0s + sb * 8, &sh[mat][idx * 8]); \
    }                                                                          \
  }

  STAGE(0);
  for (int c = 0; c < 16; ++c) {
    __syncthreads();                   // vmcnt(0): stage(c) landed in LDS
    h16x8 ah[2][4], alv[2][4], bh[2][4], blv[2][4];
#pragma unroll
    for (int kh2 = 0; kh2 < 2; ++kh2) {
#pragma unroll
      for (int mi = 0; mi < 4; ++mi) {
        int row = wm + mi * 16 + fr;
        int pp = (kh2 * 4 + quad) ^ (row & 7);
        ah[kh2][mi]  = *(const h16x8*)&sh[0][row * 64 + pp * 8];
        alv[kh2][mi] = *(const h16x8*)&sh[1][row * 64 + pp * 8];
      }
#pragma unroll
      for (int ni = 0; ni < 4; ++ni) {
        int row = wn + ni * 16 + fr;
        int pp = (kh2 * 4 + quad) ^ (row & 7);
        bh[kh2][ni]  = *(const h16x8*)&sh[2][row * 64 + pp * 8];
        blv[kh2][ni] = *(const h16x8*)&sh[3][row * 64 + pp * 8];
      }
    }
    __syncthreads();                   // all waves' ds_reads done -> LDS reusable
    if (c < 15) STAGE(c + 1);          // prefetch next chunk under the MFMAs
#pragma unroll
    for (int kh2 = 0; kh2 < 2; ++kh2)
#pragma unroll
      for (int mi = 0; mi < 4; ++mi)
#pragma unroll
        for (int ni = 0; ni < 4; ++ni) {
          acc[mi * 4 + ni] = __builtin_amdgcn_mfma_f32_16x16x32_f16(ah[kh2][mi], bh[kh2][ni], acc[mi * 4 + ni], 0, 0, 0);
          acc[mi * 4 + ni] = __builtin_amdgcn_mfma_f32_16x16x32_f16(ah[kh2][mi], blv[kh2][ni], acc[mi * 4 + ni], 0, 0, 0);
          acc[mi * 4 + ni] = __builtin_amdgcn_mfma_f32_16x16x32_f16(alv[kh2][mi], bh[kh2][ni], acc[mi * 4 + ni], 0, 0, 0);
        }
  }
#undef STAGE
#pragma unroll
  for (int mi = 0; mi < 4; ++mi)
#pragma unroll
    for (int ni = 0; ni < 4; ++ni) {
      int col = n0 + wn + ni * 16 + fr;
      int h = col >> 6, d = col & 63;
#pragma unroll
      for (int r = 0; r < 4; ++r) {
        int m = m0 + wm + mi * 16 + quad * 4 + r;
        int b = m >> 11, l = m & 2047;
        size_t off = (((size_t)b * H + h) * L + l) * 64 + d;
        float val = acc[mi * 4 + ni][r] * (1.0f / 65536.0f);
        Y[off] = val;
        _Float16 hf = (_Float16)val;
        Y16[off] = __builtin_bit_cast(unsigned short, hf);
      }
    }
}

// ---------------- Projection GEMM (fp32 scalar path — kept for V, K=64 only)
template <int K, bool EMIT>
__global__ __launch_bounds__(256) void proj_kernel(const float* __restrict__ X,
                                                   const float* __restrict__ W,
                                                   float* __restrict__ Y,
                                                   unsigned short* __restrict__ Yb,
                                                   float bscale) {
  __shared__ float As[16][128];
  __shared__ float Bs[16][64];
  const int t = threadIdx.x;
  const int tx = t & 15;
  const int ty = t >> 4;
  const int m0 = blockIdx.y * 128;
  const int n0 = blockIdx.x * 64;
  const int ar = t >> 1, ac = (t & 1) * 8;
  const int br = t >> 2, bc = (t & 3) * 4;
  const float* xg = X + (size_t)(m0 + ar) * K + ac;
  const float* wg = W + (size_t)(n0 + br) * K + bc;
  float acc[8][4] = {};
  for (int k0 = 0; k0 < K; k0 += 16) {
    float4 a0 = *(const float4*)(xg + k0);
    float4 a1 = *(const float4*)(xg + k0 + 4);
    float4 b0 = *(const float4*)(wg + k0);
    __syncthreads();
    As[ac + 0][ar] = a0.x; As[ac + 1][ar] = a0.y; As[ac + 2][ar] = a0.z; As[ac + 3][ar] = a0.w;
    As[ac + 4][ar] = a1.x; As[ac + 5][ar] = a1.y; As[ac + 6][ar] = a1.z; As[ac + 7][ar] = a1.w;
    Bs[bc + 0][br] = b0.x; Bs[bc + 1][br] = b0.y; Bs[bc + 2][br] = b0.z; Bs[bc + 3][br] = b0.w;
    __syncthreads();
#pragma unroll
    for (int kk = 0; kk < 16; ++kk) {
      float4 av0 = *(const float4*)&As[kk][ty * 8];
      float4 av1 = *(const float4*)&As[kk][ty * 8 + 4];
      float4 bv = *(const float4*)&Bs[kk][tx * 4];
      float ar8[8] = {av0.x, av0.y, av0.z, av0.w, av1.x, av1.y, av1.z, av1.w};
      float br4[4] = {bv.x, bv.y, bv.z, bv.w};
#pragma unroll
      for (int i = 0; i < 8; ++i)
#pragma unroll
        for (int j = 0; j < 4; ++j) acc[i][j] = fmaf(ar8[i], br4[j], acc[i][j]);
    }
  }
  const int n = n0 + tx * 4;
  const int h = n >> 6, d = n & 63;
#pragma unroll
  for (int i = 0; i < 8; ++i) {
    int mm = m0 + ty * 8 + i;
    int b = mm >> 11, l = mm & 2047;
    size_t off = (((size_t)b * H + h) * L + l) * 64 + d;
    *(float4*)&Y[off] = make_float4(acc[i][0], acc[i][1], acc[i][2], acc[i][3]);
  }
}

// ---------------- Approx logits, f16 MFMA -> int8 AL (quant = logit*16, clamp +-127)
constexpr int ALD = 72;    // padded LDS stride (f16 units) for frag reads
constexpr int CTB = 136;   // int8 CT stride in bytes (8-aligned, non-pow2)

__global__ __launch_bounds__(256) void alogits_kernel(const unsigned short* __restrict__ Qb,
                                                      const unsigned short* __restrict__ Kb,
                                                      char* __restrict__ AL) {
  __shared__ union {
    unsigned short qk[2][128 * ALD];   // 36864 B
    char ct[128 * CTB];                // 17408 B
  } sh;
  const int t = threadIdx.x;
  const int bh = blockIdx.z;
  const int m0 = blockIdx.y * 128, n0 = blockIdx.x * 128;
  const unsigned short* Qg = Qb + (size_t)bh * L * 64 + (size_t)m0 * 64;
  const unsigned short* Kg = Kb + (size_t)bh * L * 64 + (size_t)n0 * 64;
#pragma unroll
  for (int i = 0; i < 4; ++i) {
    int blk = t * 4 + i;               // 0..1023 : 128 rows x 8 blocks(16B)
    int r = blk >> 3, lb = blk & 7;
    *(u16x8*)&sh.qk[0][r * ALD + lb * 8] = *(const u16x8*)&Qg[r * 64 + lb * 8];
    *(u16x8*)&sh.qk[1][r * ALD + lb * 8] = *(const u16x8*)&Kg[r * 64 + lb * 8];
  }
  __syncthreads();
  const int wv = t >> 6, lane = t & 63;
  const int wm = (wv & 1) * 64, wn = (wv >> 1) * 64;
  const int fr = lane & 15, quad = lane >> 4;
  f32x4 acc[16];
#pragma unroll
  for (int i = 0; i < 16; ++i) acc[i] = (f32x4){0.f, 0.f, 0.f, 0.f};
#pragma unroll
  for (int kh = 0; kh < 2; ++kh) {
    h16x8 a[4], b[4];
#pragma unroll
    for (int mi = 0; mi < 4; ++mi)
      a[mi] = *(const h16x8*)&sh.qk[0][(wm + mi * 16 + fr) * ALD + kh * 32 + quad * 8];
#pragma unroll
    for (int ni = 0; ni < 4; ++ni)
      b[ni] = *(const h16x8*)&sh.qk[1][(wn + ni * 16 + fr) * ALD + kh * 32 + quad * 8];
#pragma unroll
    for (int mi = 0; mi < 4; ++mi)
#pragma unroll
      for (int ni = 0; ni < 4; ++ni)
        acc[mi * 4 + ni] = __builtin_amdgcn_mfma_f32_16x16x32_f16(
            a[mi], b[ni], acc[mi * 4 + ni], 0, 0, 0);
  }
  __syncthreads();                                           // reuse LDS as CT
#pragma unroll
  for (int mi = 0; mi < 4; ++mi)
#pragma unroll
    for (int ni = 0; ni < 4; ++ni) {
      int col = wn + ni * 16 + fr;
#pragma unroll
      for (int r = 0; r < 4; ++r) {
        int rowl = wm + mi * 16 + quad * 4 + r;
        float sc = acc[mi * 4 + ni][r] * 2.8571428571428572f;  // SCALE*16 (inputs unscaled f16)
        sc = fminf(fmaxf(sc, -127.0f), 127.0f);
        sh.ct[rowl * CTB + col] = (char)__float2int_rn(sc);
      }
    }
  __syncthreads();
  // Coalesced store (cached, NOT non-temporal: AL is re-read by select and fits L3)
  char* Abase = AL + (size_t)bh * L * L;
  const int rq = lane >> 4;            // 0..3
  const int cq = (lane & 15) * 8;      // 0..120, 8 B per lane
#pragma unroll
  for (int it = 0; it < 8; ++it) {
    int row = wv * 32 + it * 4 + rq;
    uint2 v8 = *(const uint2*)&sh.ct[row * CTB + cq];
    *(unsigned*)&Abase[(size_t)(m0 + row) * L + n0 + cq] = v8.x;
    *(unsigned*)&Abase[(size_t)(m0 + row) * L + n0 + cq + 4] = v8.y;
  }
}

// ---------------- Select (phase A): int8 filter -> exact fp32 recompute -> softmax
// Emits per row 32 (idx, prob) pairs. One wave per row; lane owns keys
// (u2*64+lane)*4 + b. All wave reductions via DPP; selection math identical to R3.
__global__ __launch_bounds__(256) void select_kernel(const char* __restrict__ AL,
                                                     const float* __restrict__ Qp,
                                                     const float* __restrict__ Kp,
                                                     uint2* __restrict__ Pairs) {
  __shared__ float qbuf[4][64];
  __shared__ int ibufc[4][64];
  const int lane = threadIdx.x & 63;
  const int w = threadIdx.x >> 6;
  const int row = blockIdx.x * 4 + w;
  const int bh = row >> 11;
  const int q = row & 2047;
  const unsigned long long below = (lane == 63) ? 0x7fffffffffffffffull
                                                : ((1ull << lane) - 1ull);
  const unsigned* Arow = (const unsigned*)(AL + (size_t)row * 2048);

  int li[32];
#pragma unroll
  for (int u2 = 0; u2 < 8; ++u2) {
    unsigned dw = Arow[u2 * 64 + lane];
#pragma unroll
    for (int b = 0; b < 4; ++b)
      li[u2 * 4 + b] = (int)((char)(dw >> (8 * b)));
  }
  // stage fp32 Q row (unscaled)
  if (lane < 16)
    *(float4*)&qbuf[w][lane * 4] = *(const float4*)&Qp[((size_t)bh * L + q) * 64 + lane * 4];

  // ---- exact 32nd-largest approx value on the int8 grid: 8-step bisection
  int tlo = -128, thi = 128;
#pragma unroll
  for (int it = 0; it < 8; ++it) {
    int mid = (tlo + thi) >> 1;
    int c = 0;
#pragma unroll
    for (int u = 0; u < 32; ++u) c += (li[u] >= mid) ? 1 : 0;
    c = wave_isum_dpp(c);
    if (c >= 32) tlo = mid; else thi = mid;
  }
  const int t32 = tlo;

  // ---- candidate set: largest margin whose count fits the 64 recompute slots
  int theta = t32;
  int c2 = 0;
  const int margs[5] = {6, 4, 2, 1, 0};
#pragma unroll
  for (int a = 0; a < 5; ++a) {
    int th = t32 - margs[a];
    int c = 0;
#pragma unroll
    for (int u = 0; u < 32; ++u) c += (li[u] >= th) ? 1 : 0;
    c = wave_isum_dpp(c);
    theta = th; c2 = c;
    if (c <= 64) break;
  }
  if (c2 > 64) c2 = 64;

  // rank-scatter candidate flat indices (slot order arbitrary)
  {
    int base = 0;
#pragma unroll
    for (int u = 0; u < 32; ++u) {
      bool cd = li[u] >= theta;
      unsigned long long mk = __ballot(cd);
      if (cd) {
        int s = base + __popcll(mk & below);
        if (s < 64) ibufc[w][s] = ((u >> 2) * 64 + lane) * 4 + (u & 3);
      }
      base += __popcll(mk);
    }
  }
  lds_fence();

  // ---- exact fp32 recompute for candidates (one per lane)
  int myi = (lane < c2) ? ibufc[w][lane] : 0x7fffffff;
  float vex = -FLT_MAX;
  if (lane < c2) {
    const float4* K4 = (const float4*)(Kp + ((size_t)bh * L + myi) * 64);
    const float4* Q4 = (const float4*)&qbuf[w][0];
    float acc = 0.f;
#pragma unroll
    for (int dq = 0; dq < 16; ++dq) {
      float4 kv = K4[dq];
      float4 qv = Q4[dq];
      acc = fmaf(qv.x, kv.x, acc);
      acc = fmaf(qv.y, kv.y, acc);
      acc = fmaf(qv.z, kv.z, acc);
      acc = fmaf(qv.w, kv.w, acc);
    }
    vex = (acc * 0.125f) / 0.7f;   // matches ref: (q/8)@k then /0.7
  }

  // ---- top-32 selection: bisection on sort-order bits (exact), idx-asc tie-break
  const unsigned sk = f2sort(vex);
  unsigned tb = 0;
#pragma unroll
  for (int bit = 31; bit >= 0; --bit) {
    unsigned cand = tb | (1u << bit);
    int cnt = (int)__popcll(__ballot(sk >= cand));
    if (cnt >= 32) tb = cand;
  }
  bool kept = sk > tb;
  {
    int cnt_gt = (int)__popcll(__ballot(kept));
    int need = 32 - cnt_gt;            // >= 1
    unsigned long long tiem = __ballot(sk == tb);
    if ((int)__popcll(tiem) <= need) {
      kept = kept || (sk == tb);       // all ties fit (common case)
    } else {                           // rare: pick `need` smallest indices among ties
      bool isT = (sk == tb);
      for (int r = 0; r < need; ++r) {
        int mi = wave_imin_dpp(isT ? myi : 0x7fffffff);
        if (isT && myi == mi) { kept = true; isT = false; }
      }
    }
  }

  // ---- softmax over kept 32; emit compact pairs
  float vmax = wave_fmax_dpp(vex);     // global max is kept top-1
  float e = kept ? __expf(vex - vmax) : 0.f;
  float S = wave_fsum_dpp(e);
  float p = e / S;
  {
    unsigned long long km = __ballot(kept);
    int slot = (int)__popcll(km & below);
    if (kept)
      Pairs[(size_t)row * 32 + slot] = make_uint2((unsigned)myi, __float_as_uint(p));
  }
}

// ---------------- Select (phase B): pure-BW scatter of probs + sparse PV
__global__ __launch_bounds__(256) void scatter_pv_kernel(const uint2* __restrict__ Pairs,
                                                         const float* __restrict__ Vp,
                                                         float* __restrict__ Probs,
                                                         float* __restrict__ Mixed) {
  __shared__ float prow[4][2048];
  __shared__ float pbuf[4][32];
  __shared__ int ibuf[4][32];
  const int lane = threadIdx.x & 63;
  const int w = threadIdx.x >> 6;
  const int row = blockIdx.x * 4 + w;
  const int bh = row >> 11;
  const int q = row & 2047;

  // zero prow (wave-local)
#pragma unroll
  for (int u = 0; u < 32; ++u) prow[w][u * 64 + lane] = 0.f;
  // load pairs (coalesced 256 B)
  if (lane < 32) {
    uint2 pr = Pairs[(size_t)row * 32 + lane];
    int idx = (int)pr.x;
    float p = __uint_as_float(pr.y);
    ibuf[w][lane] = idx;
    pbuf[w][lane] = p;
    prow[w][idx] = p;
  }
  lds_fence();

  // ---- dense probs row write (zeros + 32 kept)
  float* Prow = Probs + (size_t)row * 2048;
#pragma unroll
  for (int u = 0; u < 32; ++u)
    __builtin_nontemporal_store(prow[w][u * 64 + lane], Prow + u * 64 + lane);

  // ---- sparse PV
  const float* Vb = Vp + (size_t)bh * L * 64;
  float accv = 0.f;
#pragma unroll
  for (int i = 0; i < 32; ++i)
    accv = fmaf(pbuf[w][i], Vb[(size_t)ibuf[w][i] * 64 + lane], accv);
  const int bb = bh >> 4, hh = bh & 15;
  Mixed[((size_t)(bb * 2048 + q)) * 1024 + hh * 64 + lane] = accv;
}

// ---------------- Output FC: Out[m][n] = sum_k Mixed[m][k] * Wfc[n][k]  (M=4096,N=64,K=1024)
__global__ __launch_bounds__(256) void fc_kernel(const float* __restrict__ Mx,
                                                 const float* __restrict__ Wfc,
                                                 float* __restrict__ Out) {
  __shared__ float As[32][64];
  __shared__ float Ws[64][64];
  const int t = threadIdx.x;
  const int tx = t & 15;
  const int ty = t >> 4;
  const int m0 = blockIdx.x * 32;
  float acc[2][4] = {};
  for (int k0 = 0; k0 < 1024; k0 += 64) {
    __syncthreads();
    {
      int lin = t * 8;
      int rr = lin >> 6, kk = lin & 63;
      *(float4*)&As[rr][kk] = *(const float4*)&Mx[(size_t)(m0 + rr) * 1024 + k0 + kk];
      *(float4*)&As[rr][kk + 4] = *(const float4*)&Mx[(size_t)(m0 + rr) * 1024 + k0 + kk + 4];
    }
    {
      int n = t >> 2;
      int kq = (t & 3) * 16;
#pragma unroll
      for (int u = 0; u < 4; ++u) {
        float4 wv = *(const float4*)&Wfc[(size_t)n * 1024 + k0 + kq + u * 4];
        Ws[kq + u * 4 + 0][n] = wv.x;
        Ws[kq + u * 4 + 1][n] = wv.y;
        Ws[kq + u * 4 + 2][n] = wv.z;
        Ws[kq + u * 4 + 3][n] = wv.w;
      }
    }
    __syncthreads();
#pragma unroll
    for (int kk = 0; kk < 64; ++kk) {
      float a0 = As[ty][kk], a1 = As[ty + 16][kk];
      float4 wv = *(const float4*)&Ws[kk][tx * 4];
      float wr[4] = {wv.x, wv.y, wv.z, wv.w};
#pragma unroll
      for (int j = 0; j < 4; ++j) {
        acc[0][j] = fmaf(a0, wr[j], acc[0][j]);
        acc[1][j] = fmaf(a1, wr[j], acc[1][j]);
      }
    }
  }
#pragma unroll
  for (int i = 0; i < 2; ++i) {
    int mm = m0 + ty + i * 16;
    *(float4*)&Out[(size_t)mm * 64 + tx * 4] =
        make_float4(acc[i][0], acc[i][1], acc[i][2], acc[i][3]);
  }
}

extern "C" void kernel_launch(void* const* d_in, const int* in_sizes, int n_in,
                              void* d_out, int out_size, void* d_ws, size_t ws_size,
                              hipStream_t stream) {
  const float* q    = (const float*)d_in[0];
  const float* k    = (const float*)d_in[1];
  const float* v    = (const float*)d_in[2];
  const float* w_q  = (const float*)d_in[3];
  const float* w_k  = (const float*)d_in[4];
  const float* w_v  = (const float*)d_in[5];
  const float* w_fc = (const float*)d_in[6];

  float* out = (float*)d_out;
  float* probs = out + OUT0;

  float* ws = (float*)d_ws;
  float* q_proj = ws;                          // [B][H][L][64] fp32 (UNSCALED)
  float* k_proj = ws + 4194304;
  float* v_proj = ws + 8388608;
  float* mixed  = ws + 12582912;               // [B*L][1024]
  unsigned short* qb = (unsigned short*)(ws + 16777216);   // f16(q_proj) for alogits
  unsigned short* kb = (unsigned short*)(ws + 18874368);   // f16(k_proj)
  char* al = (char*)(ws + 20971520);           // approx logits int8 [bh][i][j], 128 MB

  // fp16 hi/lo split arrays (inputs * 256), placed after AL
  unsigned short* qh  = (unsigned short*)((char*)d_ws + 234881024);  // 224 MiB
  unsigned short* ql  = qh + 4194304;
  unsigned short* kh  = ql + 4194304;
  unsigned short* kl  = kh + 4194304;
  unsigned short* wqh = kl + 4194304;
  unsigned short* wql = wqh + 1048576;
  unsigned short* wkh = wql + 1048576;
  unsigned short* wkl = wkh + 1048576;
  uint2* pairs = (uint2*)((char*)d_ws + 276824064);        // 16 MB (64K rows x 32 x 8B)

  dim3 blk(256);
  split_kernel<<<dim3(1024, 4), blk, 0, stream>>>(q, k, w_q, w_k,
                                                  qh, ql, kh, kl, wqh, wql, wkh, wkl);
  proj_split_kernel<<<dim3(8, 32, 2), blk, 0, stream>>>(qh, ql, kh, kl,
                                                        wqh, wql, wkh, wkl,
                                                        q_proj, k_proj, qb, kb);
  proj_kernel<64, false><<<dim3(16, 32), blk, 0, stream>>>(v, w_v, v_proj, nullptr, 1.0f);
  alogits_kernel<<<dim3(16, 16, 32), blk, 0, stream>>>(qb, kb, al);
  select_kernel<<<dim3(16384), blk, 0, stream>>>(al, q_proj, k_proj, pairs);
  scatter_pv_kernel<<<dim3(16384), blk, 0, stream>>>(pairs, v_proj, probs, mixed);
  fc_kernel<<<dim3(128), blk, 0, stream>>>(mixed, w_fc, out);
}